// Round 11
// baseline (305.866 us; speedup 1.0000x reference)
//
#include <hip/hip_runtime.h>
#include <cstdint>
#include <cstddef>

// ---- problem constants (B=2, C=512, H=W=32, G=8, Cg=64, h2=w2=8) ----
#define BATCH 2
#define CCH   512
#define HWPIX 1024           // 32*32
#define SCALE 0.125f         // 64^-0.5

typedef short bh8 __attribute__((ext_vector_type(8)));   // 8 x bf16 (4 VGPRs)
typedef _Float16 h8 __attribute__((ext_vector_type(8))); // 8 x fp16 (4 VGPRs)
typedef _Float16 h2 __attribute__((ext_vector_type(2))); // 2 x fp16 (1 VGPR)
typedef float f32x4 __attribute__((ext_vector_type(4)));
typedef unsigned short u16;
typedef u16 us8 __attribute__((ext_vector_type(8)));     // 16B of bf16
typedef u16 us4 __attribute__((ext_vector_type(4)));     // 8B of bf16

__device__ __forceinline__ u16 f2bf(float f){
  unsigned u = __float_as_uint(f);
  unsigned r = (u + 0x7FFFu + ((u>>16)&1u))>>16;   // RNE
  return (u16)r;
}
__device__ __forceinline__ float geluf(float v){ return 0.5f*v*(1.0f + erff(v*0.70710678118654752f)); }
__device__ __forceinline__ float rdlane(float v, int l){
  return __uint_as_float(__builtin_amdgcn_readlane(__float_as_uint(v), l));
}

// ---------------- weight preconvert: f32 -> bf16, 6 segments concatenated ----------------
__global__ __launch_bounds__(256) void cvtw_kernel(
    const float* __restrict__ qw, const float* __restrict__ kw, const float* __restrict__ vw,
    const float* __restrict__ ow, const float* __restrict__ m1, const float* __restrict__ m2,
    u16* __restrict__ dst){
  int idx = (blockIdx.x*256 + threadIdx.x)*4;
  if(idx >= 2457600) return;
  const float* src; int off;
  if(idx < 32768){ src=qw; off=idx; }
  else if(idx <   65536){ src=kw; off=idx-32768; }
  else if(idx <   98304){ src=vw; off=idx-65536; }
  else if(idx <  360448){ src=ow; off=idx-98304; }
  else if(idx < 1409024){ src=m1; off=idx-360448; }
  else                  { src=m2; off=idx-1409024; }
  float4 v = *(const float4*)&src[off];
  us4 r = (us4){f2bf(v.x), f2bf(v.y), f2bf(v.z), f2bf(v.w)};
  *(us4*)&dst[idx] = r;
}

// ---------------- BatchNorm stats: per-channel scale/shift -> AB[1024] ----------------
__global__ __launch_bounds__(256) void bnstat_kernel(const float* __restrict__ src,
      const float* __restrict__ g, const float* __restrict__ bta, float* __restrict__ AB){
  int c = blockIdx.x; int t = threadIdx.x;
  float s=0.f, ss=0.f;
  for(int b=0;b<BATCH;b++){
    size_t base = (size_t)b*CCH*HWPIX + (size_t)c*HWPIX;
    for(int p=t;p<HWPIX;p+=256){
      float v = src[base+p];
      s += v; ss += v*v;
    }
  }
  for(int o=32;o;o>>=1){ s += __shfl_down(s,o); ss += __shfl_down(ss,o); }
  __shared__ float ls[4], lss[4];
  int w = t>>6, lane = t&63;
  if(lane==0){ ls[w]=s; lss[w]=ss; }
  __syncthreads();
  if(t==0){
    float S=ls[0]+ls[1]+ls[2]+ls[3], SS=lss[0]+lss[1]+lss[2]+lss[3];
    float m = S*(1.0f/2048.0f);
    float var = SS*(1.0f/2048.0f) - m*m;
    float r = rsqrtf(var + 1e-5f);
    AB[c]     = r*g[c];
    AB[512+c] = bta[c] - m*r*g[c];
  }
}

// ---------------- BN apply + transpose: src [b][ch][p] f32 -> dstT [n][k] bf16 (+opt f32 copy) ----------------
// tMode 0: dstT[(b*8+g)*65536 + p*64 + c]  (grouped, K=64)   tMode 1: dstT[b*524288 + p*512 + g*64 + c]
__global__ __launch_bounds__(256) void bntrans_kernel(const float* __restrict__ src,
      const float* __restrict__ AB, float* __restrict__ dstF, u16* __restrict__ dstT, int tMode){
  __shared__ float tile[64*65];
  int t = threadIdx.x;
  int p0 = blockIdx.x*64, gq = blockIdx.y, b = blockIdx.z;
  int pl = t&63, seg = t>>6;
  #pragma unroll
  for(int r=0;r<16;r++){
    int c = seg*16 + r;
    int ch = gq*64 + c;
    size_t a = (size_t)b*524288 + (size_t)ch*1024 + p0 + pl;
    float v = src[a]*AB[ch] + AB[512+ch];
    tile[c*65 + pl] = v;
    if(dstF) dstF[a] = v;
  }
  __syncthreads();
  int c = t&63;
  #pragma unroll
  for(int r=0;r<16;r++){
    int p = seg*16 + r;
    float v = tile[c*65 + p];
    size_t a = tMode ? ((size_t)b*524288 + (size_t)(p0+p)*512 + gq*64 + c)
                     : ((size_t)(b*8+gq)*65536 + (size_t)(p0+p)*64 + c);
    dstT[a] = f2bf(v);
  }
}

// ------- LDS-staged pipelined GEMM: out[b][m][n] = W[m][k] @ Xt, Xt is [n][k] bf16 -------
template<int TOUT>
__global__ __launch_bounds__(256) void gemm_lds(
    const u16* __restrict__ W, const u16* __restrict__ Xt,
    float* __restrict__ outF, u16* __restrict__ outT,
    const float* __restrict__ bias, const float* __restrict__ resF,
    int M, int K, int Nb, int wMask, int wStride, int doGelu){
  __shared__ __align__(16) u16 xS[64*64];   // [row][kb' swizzled], 8KB
  __shared__ __align__(16) u16 wS[64*64];   // 8KB
  int t = threadIdx.x;
  int w = t>>6, lane = t&63, l15 = lane&15, quad = lane>>4;
  int n0 = blockIdx.x*64, m0 = blockIdx.y*64, batch = blockIdx.z;
  const u16* Wg = W + (size_t)(batch & wMask)*wStride + (size_t)m0*K;
  const u16* Xg = Xt + (size_t)batch*Nb*K + (size_t)n0*K;
  int row0 = t>>3,        kb0 = t&7;
  int row1 = (256+t)>>3,  kb1 = t&7;
  const u16* pX0 = Xg + (size_t)row0*K + kb0*8;
  const u16* pX1 = Xg + (size_t)row1*K + kb1*8;
  const u16* pW0 = Wg + (size_t)row0*K + kb0*8;
  const u16* pW1 = Wg + (size_t)row1*K + kb1*8;
  u16* sX0 = &xS[(row0*8 + (kb0 ^ (row0&7)))*8];
  u16* sX1 = &xS[(row1*8 + (kb1 ^ (row1&7)))*8];
  u16* sW0 = &wS[(row0*8 + (kb0 ^ (row0&7)))*8];
  u16* sW1 = &wS[(row1*8 + (kb1 ^ (row1&7)))*8];
  f32x4 acc[4];
  #pragma unroll
  for(int mt=0;mt<4;mt++) acc[mt] = (f32x4){0.f,0.f,0.f,0.f};
  us8 rx0 = *(const us8*)pX0, rx1 = *(const us8*)pX1;
  us8 rw0 = *(const us8*)pW0, rw1 = *(const us8*)pW1;
  int rb = w*16 + l15;
  for(int kc=0;kc<K;kc+=64){
    *(us8*)sX0 = rx0;  *(us8*)sX1 = rx1;
    *(us8*)sW0 = rw0;  *(us8*)sW1 = rw1;
    __syncthreads();
    if(kc+64 < K){
      rx0 = *(const us8*)(pX0 + kc+64);  rx1 = *(const us8*)(pX1 + kc+64);
      rw0 = *(const us8*)(pW0 + kc+64);  rw1 = *(const us8*)(pW1 + kc+64);
    }
    #pragma unroll
    for(int ks=0;ks<2;ks++){
      bh8 bF = *(const bh8*)&xS[rb*64 + ((ks*4+quad) ^ (rb&7))*8];
      #pragma unroll
      for(int mt=0;mt<4;mt++){
        int ra = mt*16 + l15;
        bh8 aF = *(const bh8*)&wS[ra*64 + ((ks*4+quad) ^ (ra&7))*8];
        acc[mt] = __builtin_amdgcn_mfma_f32_16x16x32_bf16(aF, bF, acc[mt], 0,0,0);
      }
    }
    __syncthreads();
  }
  if(TOUT){
    size_t oB = (size_t)batch*Nb*(size_t)M;
    int n = n0 + w*16 + l15;
    #pragma unroll
    for(int mt=0;mt<4;mt++){
      int m = m0 + mt*16 + quad*4;
      us4 pk;
      #pragma unroll
      for(int reg=0;reg<4;reg++){
        float v = acc[mt][reg];
        if(bias) v += bias[m+reg];
        if(doGelu) v = geluf(v);
        pk[reg] = f2bf(v);
      }
      *(us4*)&outT[oB + (size_t)n*M + m] = pk;
    }
  } else {
    size_t oB = (size_t)batch*(size_t)M*Nb;
    int n = n0 + w*16 + l15;
    #pragma unroll
    for(int mt=0;mt<4;mt++)
      #pragma unroll
      for(int reg=0;reg<4;reg++){
        int m = m0 + mt*16 + quad*4 + reg;      // C/D: col=lane&15, row=quad*4+reg
        float v = acc[mt][reg];
        if(bias) v += bias[m];
        if(doGelu) v = geluf(v);
        size_t a = oB + (size_t)m*Nb + n;
        if(resF) v += resF[a];
        outF[a] = v;
      }
  }
}

// ------------- depthwise 6x6 stride-4 pad-1 conv + exact gelu -------------
__global__ __launch_bounds__(256) void dwconv_kernel(const float* __restrict__ q,
    const float* __restrict__ dw, const float* __restrict__ dwb, float* __restrict__ offg){
  int t = threadIdx.x;
  int bgc = blockIdx.x*4 + (t>>6);       // 0..1023 = bg*64 + c
  int c = bgc & 63;
  int pix = t&63;
  int oy = pix>>3, ox = pix&7;
  const float* img = q + (size_t)bgc*HWPIX;
  float acc = dwb[c];
  #pragma unroll
  for(int ky=0;ky<6;ky++){
    int y = oy*4 - 1 + ky;
    if(y<0 || y>31) continue;
    #pragma unroll
    for(int kx=0;kx<6;kx++){
      int x = ox*4 - 1 + kx;
      if(x<0 || x>31) continue;
      acc = fmaf(img[y*32 + x], dw[c*36 + ky*6 + kx], acc);
    }
  }
  offg[(size_t)bgc*64 + pix] = geluf(acc);
}

// ------------- pointwise 64->2, tanh*4, build sampling grid -------------
__global__ __launch_bounds__(64) void pwgrid_kernel(const float* __restrict__ offg,
    const float* __restrict__ pw, float* __restrict__ vgrid){
  int bg = blockIdx.x; int p = threadIdx.x;
  float a0=0.f, a1=0.f;
  for(int c=0;c<64;c++){
    float v = offg[(size_t)bg*4096 + c*64 + p];
    a0 = fmaf(v, pw[c], a0);
    a1 = fmaf(v, pw[64+c], a1);
  }
  float o0 = tanhf(a0)*4.0f, o1 = tanhf(a1)*4.0f;
  float gx = (float)(p&7), gy = (float)(p>>3);
  float vxx = (2.0f/7.0f)*(gx + o0) - 1.0f;
  float vyy = (2.0f/7.0f)*(gy + o1) - 1.0f;
  vgrid[bg*128 + p*2]     = vxx;
  vgrid[bg*128 + p*2 + 1] = vyy;
}

// ------------- bilinear grid sample (zero padding), bf16 [p][c] output -------------
__device__ __forceinline__ float fetchpix(const float* img, int ix, int iy){
  return (ix>=0 && ix<32 && iy>=0 && iy<32) ? img[iy*32+ix] : 0.0f;
}
__global__ __launch_bounds__(256) void sample_kernel(const float* __restrict__ xn,
    const float* __restrict__ vgrid, u16* __restrict__ kvT){
  int bg = blockIdx.x; int t = threadIdx.x;
  int p = t&63, cblk = t>>6;
  float vx = vgrid[bg*128 + p*2], vy = vgrid[bg*128 + p*2+1];
  float xs = ((vx + 1.0f)*32.0f - 1.0f)*0.5f;
  float ys = ((vy + 1.0f)*32.0f - 1.0f)*0.5f;
  float x0 = floorf(xs), y0 = floorf(ys);
  float wx = xs - x0, wy = ys - y0;
  int ix0 = (int)x0, iy0 = (int)y0;
  int b = bg>>3, g = bg&7;
  float w00 = (1.f-wx)*(1.f-wy), w10 = wx*(1.f-wy), w01 = (1.f-wx)*wy, w11 = wx*wy;
  u16 tmp[16];
  for(int cc=0;cc<16;cc++){
    int c = cblk*16 + cc;
    const float* img = xn + (size_t)b*CCH*HWPIX + (size_t)(g*64+c)*HWPIX;
    float acc = w00*fetchpix(img,ix0,iy0)   + w10*fetchpix(img,ix0+1,iy0)
              + w01*fetchpix(img,ix0,iy0+1) + w11*fetchpix(img,ix0+1,iy0+1);
    tmp[cc] = f2bf(acc);
  }
  *(us8*)&kvT[(size_t)bg*4096 + p*64 + cblk*16]     = *(us8*)&tmp[0];
  *(us8*)&kvT[(size_t)bg*4096 + p*64 + cblk*16 + 8] = *(us8*)&tmp[8];
}

// ------------- CPB bias MLP v3 (R9 body): packed-f16 layer-0, f16 MFMA layer-1 -------------
// ONLY change vs R9: __launch_bounds__(256) — no waves-per-EU arg (it was capping occupancy).
// Output layout: biasOut[bg][j][i]
__global__ __launch_bounds__(256) void biasmlp_kernel(
    const float* __restrict__ w0, const float* __restrict__ b0,
    const float* __restrict__ w1, const float* __restrict__ b1,
    const float* __restrict__ w2, const float* __restrict__ b2,
    const float* __restrict__ vgrid, float* __restrict__ biasOut){
  __shared__ __align__(16) _Float16 w1h[128*136];   // W1 transposed: [n][k] f16
  int t = threadIdx.x;
  int bg = blockIdx.x >> 6, jj = blockIdx.x & 63;
  for(int e=t;e<16384;e+=256){
    int k = e>>7, n = e&127;
    w1h[n*136 + k] = (_Float16)w1[e];             // w1 is [k][n] row-major f32
  }
  float vx = vgrid[bg*128 + jj*2];
  float vy = vgrid[bg*128 + jj*2 + 1];
  int lane = t&63, w = t>>6, l15 = lane&15, quad = lane>>4;
  int gxi = (w*16 + l15)&31;
  float px = (2.0f/31.0f)*(float)gxi - 1.0f - vx;
  float u = copysignf(__logf(1.0f + fabsf(px)), px);
  h2 t1p[16], wyp[16];
  #pragma unroll
  for(int ks=0;ks<4;ks++){
    #pragma unroll
    for(int d=0;d<4;d++){
      int k = ks*32 + quad*8 + 2*d;
      t1p[ks*4+d] = (h2){(_Float16)fmaf(u, w0[k], b0[k]), (_Float16)fmaf(u, w0[k+1], b0[k+1])};
      wyp[ks*4+d] = (h2){(_Float16)w0[128+k], (_Float16)w0[128+k+1]};
    }
  }
  __syncthreads();
  h8 bfr[8][4];
  float b1f[8], w2f[8];
  #pragma unroll
  for(int nt=0;nt<8;nt++){
    int n = nt*16 + l15;
    b1f[nt] = b1[n];
    w2f[nt] = w2[n];
    #pragma unroll
    for(int ks=0;ks<4;ks++)
      bfr[nt][ks] = *(const h8*)&w1h[n*136 + ks*32 + quad*8];
  }
  float b2v = b2[0];
  const h2 z2 = (h2){(_Float16)0.f, (_Float16)0.f};
  float* outP = biasOut + (size_t)bg*65536 + (size_t)jj*1024;
  for(int s=0;s<16;s++){
    int gyi = (s*64 + w*16 + l15)>>5;
    float py = (2.0f/31.0f)*(float)gyi - 1.0f - vy;
    float v = copysignf(__logf(1.0f + fabsf(py)), py);
    _Float16 vh = (_Float16)v;
    h2 v2 = (h2){vh, vh};
    union { h2 p[4]; h8 v8; } ah[4];
    #pragma unroll
    for(int ks=0;ks<4;ks++){
      #pragma unroll
      for(int d=0;d<4;d++)
        ah[ks].p[d] = __builtin_elementwise_max(v2*wyp[ks*4+d] + t1p[ks*4+d], z2);
    }
    f32x4 acc[8];
    #pragma unroll
    for(int nt=0;nt<8;nt++)
      acc[nt] = (f32x4){b1f[nt], b1f[nt], b1f[nt], b1f[nt]};
    #pragma unroll
    for(int ks=0;ks<4;ks++){
      #pragma unroll
      for(int nt=0;nt<8;nt++)
        acc[nt] = __builtin_amdgcn_mfma_f32_16x16x32_f16(ah[ks].v8, bfr[nt][ks], acc[nt],0,0,0);
    }
    float pr[4];
    #pragma unroll
    for(int reg=0;reg<4;reg++){
      float p = 0.f;
      #pragma unroll
      for(int nt=0;nt<8;nt++)
        p = fmaf(fmaxf(acc[nt][reg], 0.0f), w2f[nt], p);
      p += __shfl_xor(p, 1);
      p += __shfl_xor(p, 2);
      p += __shfl_xor(p, 4);
      p += __shfl_xor(p, 8);
      pr[reg] = p + b2v;
    }
    if(l15==0){
      *(f32x4*)&outP[s*64 + w*16 + quad*4] = (f32x4){pr[0], pr[1], pr[2], pr[3]};
    }
  }
}

// ------------- attention: softmax(q·K*scale + bias) @ V, output [b][p][ch] bf16 -------------
__global__ __launch_bounds__(256) void attn_kernel(
    const float* __restrict__ qb, const float* __restrict__ kb, const float* __restrict__ vb,
    const float* __restrict__ biasb, u16* __restrict__ obT){
  __shared__ float qT[64*65], kT[64*65], vT[64*65], bT[64*65];
  int t = threadIdx.x;
  int bg = blockIdx.x>>4, itile = blockIdx.x&15;
  int i0 = itile*64;
  size_t qBase = (size_t)bg*65536;        // == b*C*HW + g*64*HW
  for(int e=t;e<4096;e+=256){
    int d = e>>6, x = e&63;
    qT[d*65 + x] = qb[qBase + (size_t)d*HWPIX + i0 + x];
    kT[d*65 + x] = kb[(size_t)bg*4096 + e];
    vT[d*65 + x] = vb[(size_t)bg*4096 + e];
    bT[x*65 + d] = biasb[(size_t)bg*65536 + (size_t)d*1024 + i0 + x];  // d=j, x=il
  }
  __syncthreads();
  int lane = t&63, w = t>>6;
  int b = bg>>3, g = bg&7;
  for(int rr=0;rr<16;rr++){
    int il = w*16 + rr;
    int i = i0 + il;
    float qreg = qT[lane*65 + il];     // lane l holds q[i][d=l]
    float s0=0.f,s1=0.f,s2=0.f,s3=0.f;
    #pragma unroll 4
    for(int d=0;d<64;d+=4){
      s0 = fmaf(rdlane(qreg,d  ), kT[(d  )*65 + lane], s0);
      s1 = fmaf(rdlane(qreg,d+1), kT[(d+1)*65 + lane], s1);
      s2 = fmaf(rdlane(qreg,d+2), kT[(d+2)*65 + lane], s2);
      s3 = fmaf(rdlane(qreg,d+3), kT[(d+3)*65 + lane], s3);
    }
    float s = (s0+s1)+(s2+s3);
    s = s*SCALE + bT[il*65 + lane];
    float m = s;
    for(int msk=32;msk;msk>>=1) m = fmaxf(m, __shfl_xor(m, msk));
    float p = __expf(s - m);
    float l = p;
    for(int msk=32;msk;msk>>=1) l += __shfl_xor(l, msk);
    p = p / l;
    float o0=0.f,o1=0.f,o2=0.f,o3=0.f;
    #pragma unroll 4
    for(int j=0;j<64;j+=4){
      o0 = fmaf(rdlane(p,j  ), vT[lane*65 + j  ], o0);
      o1 = fmaf(rdlane(p,j+1), vT[lane*65 + j+1], o1);
      o2 = fmaf(rdlane(p,j+2), vT[lane*65 + j+2], o2);
      o3 = fmaf(rdlane(p,j+3), vT[lane*65 + j+3], o3);
    }
    obT[(size_t)b*524288 + (size_t)i*512 + g*64 + lane] = f2bf((o0+o1)+(o2+o3));
  }
}

extern "C" void kernel_launch(void* const* d_in, const int* in_sizes, int n_in,
                              void* d_out, int out_size, void* d_ws, size_t ws_size,
                              hipStream_t stream){
  const float* x    = (const float*)d_in[0];
  const float* n1g  = (const float*)d_in[1];
  const float* n1b  = (const float*)d_in[2];
  const float* n2g  = (const float*)d_in[3];
  const float* n2b  = (const float*)d_in[4];
  const float* qw   = (const float*)d_in[5];
  const float* kw   = (const float*)d_in[6];
  const float* vw   = (const float*)d_in[7];
  const float* dww  = (const float*)d_in[8];
  const float* dwb  = (const float*)d_in[9];
  const float* pww  = (const float*)d_in[10];
  const float* cw0  = (const float*)d_in[11];
  const float* cb0  = (const float*)d_in[12];
  const float* cw1  = (const float*)d_in[13];
  const float* cb1  = (const float*)d_in[14];
  const float* cw2  = (const float*)d_in[15];
  const float* cb2  = (const float*)d_in[16];
  const float* ow   = (const float*)d_in[17];
  const float* obb  = (const float*)d_in[18];
  const float* m1w  = (const float*)d_in[19];
  const float* m1bi = (const float*)d_in[20];
  const float* m2w  = (const float*)d_in[21];
  const float* m2bi = (const float*)d_in[22];
  float* out = (float*)d_out;          // reference output dtype is float32
  float* ws = (float*)d_ws;

  float* xn     = ws;                       // 1M f32: bn1 normalized (c-major, for sample)
  float* x2     = ws + 1048576;             // 1M f32: outproj out (res for mlp2, src for bn2)
  float* q      = ws + 2097152;             // 1M f32, dead after attn
  float* biasb  = ws + 3145728;             // 1M f32, dead after attn
  u16*   hT     = (u16*)(ws + 2097152);     // 4M u16 over dead {q,biasb}: mlp1 out [b][p][c2048]
  u16*   attnT  = (u16*)(ws + 4194304);     // 1M u16: attn out [b][p][c512]
  u16*   xnT    = (u16*)(ws + 4718592);     // 1M u16: bn1 T [bg][p][c64]; reused as bn2 T [b][p][c512]
  u16*   kvT    = (u16*)(ws + 5242880);     // 64K u16: [bg][p][c64]
  float* kbuf   = ws + 5275648;             // 64K f32
  float* vbuf   = ws + 5341184;             // 64K f32
  float* offg   = ws + 5406720;             // 64K f32 (aliased as bn stats when offg dead)
  float* bnAB   = offg;                     // 1024 f32 alias (disjoint lifetime)
  float* vgrid  = ws + 5472256;             // 2K f32
  u16*   wbf    = (u16*)(ws + 5474304);     // 2457600 u16 bf16 weights
  u16 *qwb = wbf, *kwb = wbf+32768, *vwb = wbf+65536, *owb = wbf+98304;
  u16 *m1wb = wbf+360448, *m2wb = wbf+1409024;

  cvtw_kernel<<<2400,256,0,stream>>>(qw,kw,vw,ow,m1w,m2w,wbf);
  bnstat_kernel<<<512,256,0,stream>>>(x, n1g, n1b, bnAB);
  bntrans_kernel<<<dim3(16,8,2),256,0,stream>>>(x, bnAB, xn, xnT, 0);
  gemm_lds<0><<<dim3(16,1,16),256,0,stream>>>(qwb, xnT, q, nullptr, nullptr, nullptr,
                                              64,64,1024, 7, 4096, 0);
  dwconv_kernel<<<256,256,0,stream>>>(q, dww, dwb, offg);
  pwgrid_kernel<<<16,64,0,stream>>>(offg, pww, vgrid);
  sample_kernel<<<16,256,0,stream>>>(xn, vgrid, kvT);
  gemm_lds<0><<<dim3(1,1,16),256,0,stream>>>(kwb, kvT, kbuf, nullptr, nullptr, nullptr,
                                             64,64,64, 7, 4096, 0);
  gemm_lds<0><<<dim3(1,1,16),256,0,stream>>>(vwb, kvT, vbuf, nullptr, nullptr, nullptr,
                                             64,64,64, 7, 4096, 0);
  biasmlp_kernel<<<1024,256,0,stream>>>(cw0, cb0, cw1, cb1, cw2, cb2, vgrid, biasb);
  attn_kernel<<<256,256,0,stream>>>(q, kbuf, vbuf, biasb, attnT);
  gemm_lds<0><<<dim3(16,8,2),256,0,stream>>>(owb, attnT, x2, nullptr, obb, x,
                                             512,512,1024, 0,0,0);
  bnstat_kernel<<<512,256,0,stream>>>(x2, n2g, n2b, bnAB);
  bntrans_kernel<<<dim3(16,8,2),256,0,stream>>>(x2, bnAB, nullptr, xnT, 1);
  gemm_lds<1><<<dim3(16,32,2),256,0,stream>>>(m1wb, xnT, nullptr, hT, m1bi, nullptr,
                                              2048,512,1024, 0,0,1);
  gemm_lds<0><<<dim3(16,8,2),256,0,stream>>>(m2wb, hT, out, nullptr, m2bi, x2,
                                             512,2048,1024, 0,0,0);
}

// Round 12
// 285.277 us; speedup vs baseline: 1.0722x; 1.0722x over previous
//
#include <hip/hip_runtime.h>
#include <cstdint>
#include <cstddef>

// ---- problem constants (B=2, C=512, H=W=32, G=8, Cg=64, h2=w2=8) ----
#define BATCH 2
#define CCH   512
#define HWPIX 1024           // 32*32
#define SCALE 0.125f         // 64^-0.5

typedef short bh8 __attribute__((ext_vector_type(8)));   // 8 x bf16 (4 VGPRs)
typedef _Float16 h8 __attribute__((ext_vector_type(8))); // 8 x fp16 (4 VGPRs)
typedef _Float16 h2 __attribute__((ext_vector_type(2))); // 2 x fp16 (1 VGPR)
typedef float f32x4 __attribute__((ext_vector_type(4)));
typedef float f32x2 __attribute__((ext_vector_type(2)));
typedef unsigned short u16;
typedef u16 us8 __attribute__((ext_vector_type(8)));     // 16B of bf16
typedef u16 us4 __attribute__((ext_vector_type(4)));     // 8B of bf16

__device__ __forceinline__ u16 f2bf(float f){
  unsigned u = __float_as_uint(f);
  unsigned r = (u + 0x7FFFu + ((u>>16)&1u))>>16;   // RNE
  return (u16)r;
}
__device__ __forceinline__ float geluf(float v){ return 0.5f*v*(1.0f + erff(v*0.70710678118654752f)); }
__device__ __forceinline__ float rdlane(float v, int l){
  return __uint_as_float(__builtin_amdgcn_readlane(__float_as_uint(v), l));
}

// ---------------- weight preconvert: f32 -> bf16, 6 segments concatenated ----------------
__global__ __launch_bounds__(256) void cvtw_kernel(
    const float* __restrict__ qw, const float* __restrict__ kw, const float* __restrict__ vw,
    const float* __restrict__ ow, const float* __restrict__ m1, const float* __restrict__ m2,
    u16* __restrict__ dst){
  int idx = (blockIdx.x*256 + threadIdx.x)*4;
  if(idx >= 2457600) return;
  const float* src; int off;
  if(idx < 32768){ src=qw; off=idx; }
  else if(idx <   65536){ src=kw; off=idx-32768; }
  else if(idx <   98304){ src=vw; off=idx-65536; }
  else if(idx <  360448){ src=ow; off=idx-98304; }
  else if(idx < 1409024){ src=m1; off=idx-360448; }
  else                  { src=m2; off=idx-1409024; }
  float4 v = *(const float4*)&src[off];
  us4 r = (us4){f2bf(v.x), f2bf(v.y), f2bf(v.z), f2bf(v.w)};
  *(us4*)&dst[idx] = r;
}

// ---------------- BatchNorm stats: per-channel scale/shift -> AB[1024] ----------------
__global__ __launch_bounds__(256) void bnstat_kernel(const float* __restrict__ src,
      const float* __restrict__ g, const float* __restrict__ bta, float* __restrict__ AB){
  int c = blockIdx.x; int t = threadIdx.x;
  float s=0.f, ss=0.f;
  for(int b=0;b<BATCH;b++){
    size_t base = (size_t)b*CCH*HWPIX + (size_t)c*HWPIX;
    for(int p=t;p<HWPIX;p+=256){
      float v = src[base+p];
      s += v; ss += v*v;
    }
  }
  for(int o=32;o;o>>=1){ s += __shfl_down(s,o); ss += __shfl_down(ss,o); }
  __shared__ float ls[4], lss[4];
  int w = t>>6, lane = t&63;
  if(lane==0){ ls[w]=s; lss[w]=ss; }
  __syncthreads();
  if(t==0){
    float S=ls[0]+ls[1]+ls[2]+ls[3], SS=lss[0]+lss[1]+lss[2]+lss[3];
    float m = S*(1.0f/2048.0f);
    float var = SS*(1.0f/2048.0f) - m*m;
    float r = rsqrtf(var + 1e-5f);
    AB[c]     = r*g[c];
    AB[512+c] = bta[c] - m*r*g[c];
  }
}

// ---------------- BN apply + transpose: src [b][ch][p] f32 -> dstT [n][k] bf16 (+opt f32 copy) ----------------
// tMode 0: dstT[(b*8+g)*65536 + p*64 + c]  (grouped, K=64)   tMode 1: dstT[b*524288 + p*512 + g*64 + c]
__global__ __launch_bounds__(256) void bntrans_kernel(const float* __restrict__ src,
      const float* __restrict__ AB, float* __restrict__ dstF, u16* __restrict__ dstT, int tMode){
  __shared__ float tile[64*65];
  int t = threadIdx.x;
  int p0 = blockIdx.x*64, gq = blockIdx.y, b = blockIdx.z;
  int pl = t&63, seg = t>>6;
  #pragma unroll
  for(int r=0;r<16;r++){
    int c = seg*16 + r;
    int ch = gq*64 + c;
    size_t a = (size_t)b*524288 + (size_t)ch*1024 + p0 + pl;
    float v = src[a]*AB[ch] + AB[512+ch];
    tile[c*65 + pl] = v;
    if(dstF) dstF[a] = v;
  }
  __syncthreads();
  int c = t&63;
  #pragma unroll
  for(int r=0;r<16;r++){
    int p = seg*16 + r;
    float v = tile[c*65 + p];
    size_t a = tMode ? ((size_t)b*524288 + (size_t)(p0+p)*512 + gq*64 + c)
                     : ((size_t)(b*8+gq)*65536 + (size_t)(p0+p)*64 + c);
    dstT[a] = f2bf(v);
  }
}

// ------- LDS-staged pipelined GEMM: out[b][m][n] = W[m][k] @ Xt, Xt is [n][k] bf16 -------
// (256,4): cap VGPR at 128 so 4 waves/SIMD can hide staging latency (usage ~70-90, no spill).
template<int TOUT>
__global__ __launch_bounds__(256,4) void gemm_lds(
    const u16* __restrict__ W, const u16* __restrict__ Xt,
    float* __restrict__ outF, u16* __restrict__ outT,
    const float* __restrict__ bias, const float* __restrict__ resF,
    int M, int K, int Nb, int wMask, int wStride, int doGelu){
  __shared__ __align__(16) u16 xS[64*64];   // [row][kb' swizzled], 8KB
  __shared__ __align__(16) u16 wS[64*64];   // 8KB
  int t = threadIdx.x;
  int w = t>>6, lane = t&63, l15 = lane&15, quad = lane>>4;
  int n0 = blockIdx.x*64, m0 = blockIdx.y*64, batch = blockIdx.z;
  const u16* Wg = W + (size_t)(batch & wMask)*wStride + (size_t)m0*K;
  const u16* Xg = Xt + (size_t)batch*Nb*K + (size_t)n0*K;
  int row0 = t>>3,        kb0 = t&7;
  int row1 = (256+t)>>3,  kb1 = t&7;
  const u16* pX0 = Xg + (size_t)row0*K + kb0*8;
  const u16* pX1 = Xg + (size_t)row1*K + kb1*8;
  const u16* pW0 = Wg + (size_t)row0*K + kb0*8;
  const u16* pW1 = Wg + (size_t)row1*K + kb1*8;
  u16* sX0 = &xS[(row0*8 + (kb0 ^ (row0&7)))*8];
  u16* sX1 = &xS[(row1*8 + (kb1 ^ (row1&7)))*8];
  u16* sW0 = &wS[(row0*8 + (kb0 ^ (row0&7)))*8];
  u16* sW1 = &wS[(row1*8 + (kb1 ^ (row1&7)))*8];
  f32x4 acc[4];
  #pragma unroll
  for(int mt=0;mt<4;mt++) acc[mt] = (f32x4){0.f,0.f,0.f,0.f};
  us8 rx0 = *(const us8*)pX0, rx1 = *(const us8*)pX1;
  us8 rw0 = *(const us8*)pW0, rw1 = *(const us8*)pW1;
  int rb = w*16 + l15;
  for(int kc=0;kc<K;kc+=64){
    *(us8*)sX0 = rx0;  *(us8*)sX1 = rx1;
    *(us8*)sW0 = rw0;  *(us8*)sW1 = rw1;
    __syncthreads();
    if(kc+64 < K){
      rx0 = *(const us8*)(pX0 + kc+64);  rx1 = *(const us8*)(pX1 + kc+64);
      rw0 = *(const us8*)(pW0 + kc+64);  rw1 = *(const us8*)(pW1 + kc+64);
    }
    #pragma unroll
    for(int ks=0;ks<2;ks++){
      bh8 bF = *(const bh8*)&xS[rb*64 + ((ks*4+quad) ^ (rb&7))*8];
      #pragma unroll
      for(int mt=0;mt<4;mt++){
        int ra = mt*16 + l15;
        bh8 aF = *(const bh8*)&wS[ra*64 + ((ks*4+quad) ^ (ra&7))*8];
        acc[mt] = __builtin_amdgcn_mfma_f32_16x16x32_bf16(aF, bF, acc[mt], 0,0,0);
      }
    }
    __syncthreads();
  }
  if(TOUT){
    size_t oB = (size_t)batch*Nb*(size_t)M;
    int n = n0 + w*16 + l15;
    #pragma unroll
    for(int mt=0;mt<4;mt++){
      int m = m0 + mt*16 + quad*4;
      us4 pk;
      #pragma unroll
      for(int reg=0;reg<4;reg++){
        float v = acc[mt][reg];
        if(bias) v += bias[m+reg];
        if(doGelu) v = geluf(v);
        pk[reg] = f2bf(v);
      }
      *(us4*)&outT[oB + (size_t)n*M + m] = pk;
    }
  } else {
    size_t oB = (size_t)batch*(size_t)M*Nb;
    int n = n0 + w*16 + l15;
    #pragma unroll
    for(int mt=0;mt<4;mt++)
      #pragma unroll
      for(int reg=0;reg<4;reg++){
        int m = m0 + mt*16 + quad*4 + reg;      // C/D: col=lane&15, row=quad*4+reg
        float v = acc[mt][reg];
        if(bias) v += bias[m];
        if(doGelu) v = geluf(v);
        size_t a = oB + (size_t)m*Nb + n;
        if(resF) v += resF[a];
        outF[a] = v;
      }
  }
}

// ------------- depthwise 6x6 stride-4 pad-1 conv + exact gelu -------------
__global__ __launch_bounds__(256) void dwconv_kernel(const float* __restrict__ q,
    const float* __restrict__ dw, const float* __restrict__ dwb, float* __restrict__ offg){
  int t = threadIdx.x;
  int bgc = blockIdx.x*4 + (t>>6);       // 0..1023 = bg*64 + c
  int c = bgc & 63;
  int pix = t&63;
  int oy = pix>>3, ox = pix&7;
  const float* img = q + (size_t)bgc*HWPIX;
  float acc = dwb[c];
  #pragma unroll
  for(int ky=0;ky<6;ky++){
    int y = oy*4 - 1 + ky;
    if(y<0 || y>31) continue;
    #pragma unroll
    for(int kx=0;kx<6;kx++){
      int x = ox*4 - 1 + kx;
      if(x<0 || x>31) continue;
      acc = fmaf(img[y*32 + x], dw[c*36 + ky*6 + kx], acc);
    }
  }
  offg[(size_t)bgc*64 + pix] = geluf(acc);
}

// ------------- pointwise 64->2, tanh*4, build sampling grid -------------
__global__ __launch_bounds__(64) void pwgrid_kernel(const float* __restrict__ offg,
    const float* __restrict__ pw, float* __restrict__ vgrid){
  int bg = blockIdx.x; int p = threadIdx.x;
  float a0=0.f, a1=0.f;
  for(int c=0;c<64;c++){
    float v = offg[(size_t)bg*4096 + c*64 + p];
    a0 = fmaf(v, pw[c], a0);
    a1 = fmaf(v, pw[64+c], a1);
  }
  float o0 = tanhf(a0)*4.0f, o1 = tanhf(a1)*4.0f;
  float gx = (float)(p&7), gy = (float)(p>>3);
  float vxx = (2.0f/7.0f)*(gx + o0) - 1.0f;
  float vyy = (2.0f/7.0f)*(gy + o1) - 1.0f;
  vgrid[bg*128 + p*2]     = vxx;
  vgrid[bg*128 + p*2 + 1] = vyy;
}

// ------------- bilinear grid sample (zero padding), bf16 [p][c] output -------------
__device__ __forceinline__ float fetchpix(const float* img, int ix, int iy){
  return (ix>=0 && ix<32 && iy>=0 && iy<32) ? img[iy*32+ix] : 0.0f;
}
__global__ __launch_bounds__(256) void sample_kernel(const float* __restrict__ xn,
    const float* __restrict__ vgrid, u16* __restrict__ kvT){
  int bg = blockIdx.x; int t = threadIdx.x;
  int p = t&63, cblk = t>>6;
  float vx = vgrid[bg*128 + p*2], vy = vgrid[bg*128 + p*2+1];
  float xs = ((vx + 1.0f)*32.0f - 1.0f)*0.5f;
  float ys = ((vy + 1.0f)*32.0f - 1.0f)*0.5f;
  float x0 = floorf(xs), y0 = floorf(ys);
  float wx = xs - x0, wy = ys - y0;
  int ix0 = (int)x0, iy0 = (int)y0;
  int b = bg>>3, g = bg&7;
  float w00 = (1.f-wx)*(1.f-wy), w10 = wx*(1.f-wy), w01 = (1.f-wx)*wy, w11 = wx*wy;
  u16 tmp[16];
  for(int cc=0;cc<16;cc++){
    int c = cblk*16 + cc;
    const float* img = xn + (size_t)b*CCH*HWPIX + (size_t)(g*64+c)*HWPIX;
    float acc = w00*fetchpix(img,ix0,iy0)   + w10*fetchpix(img,ix0+1,iy0)
              + w01*fetchpix(img,ix0,iy0+1) + w11*fetchpix(img,ix0+1,iy0+1);
    tmp[cc] = f2bf(acc);
  }
  *(us8*)&kvT[(size_t)bg*4096 + p*64 + cblk*16]     = *(us8*)&tmp[0];
  *(us8*)&kvT[(size_t)bg*4096 + p*64 + cblk*16 + 8] = *(us8*)&tmp[8];
}

// ------------- CPB bias MLP v5: R9 body + b1-fold into MFMA C + packed-f32 epilogue -------------
// (256,2) is the proven best config (R11 falsified removing it). Output: biasOut[bg][j][i]
__global__ __launch_bounds__(256,2) void biasmlp_kernel(
    const float* __restrict__ w0, const float* __restrict__ b0,
    const float* __restrict__ w1, const float* __restrict__ b1,
    const float* __restrict__ w2, const float* __restrict__ b2,
    const float* __restrict__ vgrid, float* __restrict__ biasOut){
  __shared__ __align__(16) _Float16 w1h[128*136];   // W1 transposed: [n][k] f16
  int t = threadIdx.x;
  int bg = blockIdx.x >> 6, jj = blockIdx.x & 63;
  for(int e=t;e<16384;e+=256){
    int k = e>>7, n = e&127;
    w1h[n*136 + k] = (_Float16)w1[e];             // w1 is [k][n] row-major f32
  }
  float vx = vgrid[bg*128 + jj*2];
  float vy = vgrid[bg*128 + jj*2 + 1];
  int lane = t&63, w = t>>6, l15 = lane&15, quad = lane>>4;
  int gxi = (w*16 + l15)&31;
  float px = (2.0f/31.0f)*(float)gxi - 1.0f - vx;
  float u = copysignf(__logf(1.0f + fabsf(px)), px);
  h2 t1p[16], wyp[16];
  #pragma unroll
  for(int ks=0;ks<4;ks++){
    #pragma unroll
    for(int d=0;d<4;d++){
      int k = ks*32 + quad*8 + 2*d;
      t1p[ks*4+d] = (h2){(_Float16)fmaf(u, w0[k], b0[k]), (_Float16)fmaf(u, w0[k+1], b0[k+1])};
      wyp[ks*4+d] = (h2){(_Float16)w0[128+k], (_Float16)w0[128+k+1]};
    }
  }
  __syncthreads();
  h8 bfr[8][4];
  f32x4 b1c[8];            // b1 splat, used as MFMA C operand (kills 32 acc-init movs/s)
  float w2f[8];
  #pragma unroll
  for(int nt=0;nt<8;nt++){
    int n = nt*16 + l15;
    float bv = b1[n];
    b1c[nt] = (f32x4){bv, bv, bv, bv};
    w2f[nt] = w2[n];
    #pragma unroll
    for(int ks=0;ks<4;ks++)
      bfr[nt][ks] = *(const h8*)&w1h[n*136 + ks*32 + quad*8];
  }
  float b2v = b2[0];
  const h2 z2 = (h2){(_Float16)0.f, (_Float16)0.f};
  const f32x2 zf2 = (f32x2){0.f, 0.f};
  float* outP = biasOut + (size_t)bg*65536 + (size_t)jj*1024;
  for(int s=0;s<16;s++){
    int gyi = (s*64 + w*16 + l15)>>5;
    float py = (2.0f/31.0f)*(float)gyi - 1.0f - vy;
    float v = copysignf(__logf(1.0f + fabsf(py)), py);
    _Float16 vh = (_Float16)v;
    h2 v2 = (h2){vh, vh};
    union { h2 p[4]; h8 v8; } ah[4];
    #pragma unroll
    for(int ks=0;ks<4;ks++){
      #pragma unroll
      for(int d=0;d<4;d++)
        ah[ks].p[d] = __builtin_elementwise_max(v2*wyp[ks*4+d] + t1p[ks*4+d], z2);
    }
    // layer-1: first K-step consumes b1c as C (no init movs)
    f32x4 acc[8];
    #pragma unroll
    for(int nt=0;nt<8;nt++)
      acc[nt] = __builtin_amdgcn_mfma_f32_16x16x32_f16(ah[0].v8, bfr[nt][0], b1c[nt],0,0,0);
    #pragma unroll
    for(int ks=1;ks<4;ks++){
      #pragma unroll
      for(int nt=0;nt<8;nt++)
        acc[nt] = __builtin_amdgcn_mfma_f32_16x16x32_f16(ah[ks].v8, bfr[nt][ks], acc[nt],0,0,0);
    }
    // layer-2 epilogue, packed f32 (v_pk_max/v_pk_fma): regs pair (0,1) and (2,3)
    f32x2 p01 = zf2, p23 = zf2;
    #pragma unroll
    for(int nt=0;nt<8;nt++){
      f32x2 w2p = (f32x2){w2f[nt], w2f[nt]};
      f32x2 h01 = __builtin_elementwise_max((f32x2){acc[nt][0], acc[nt][1]}, zf2);
      f32x2 h23 = __builtin_elementwise_max((f32x2){acc[nt][2], acc[nt][3]}, zf2);
      p01 = h01*w2p + p01;
      p23 = h23*w2p + p23;
    }
    float pr[4] = {p01[0], p01[1], p23[0], p23[1]};
    #pragma unroll
    for(int reg=0;reg<4;reg++){
      float p = pr[reg];
      p += __shfl_xor(p, 1);
      p += __shfl_xor(p, 2);
      p += __shfl_xor(p, 4);
      p += __shfl_xor(p, 8);
      pr[reg] = p + b2v;
    }
    if(l15==0){
      *(f32x4*)&outP[s*64 + w*16 + quad*4] = (f32x4){pr[0], pr[1], pr[2], pr[3]};
    }
  }
}

// ------------- attention: softmax(q·K*scale + bias) @ V, output [b][p][ch] bf16 -------------
__global__ __launch_bounds__(256) void attn_kernel(
    const float* __restrict__ qb, const float* __restrict__ kb, const float* __restrict__ vb,
    const float* __restrict__ biasb, u16* __restrict__ obT){
  __shared__ float qT[64*65], kT[64*65], vT[64*65], bT[64*65];
  int t = threadIdx.x;
  int bg = blockIdx.x>>4, itile = blockIdx.x&15;
  int i0 = itile*64;
  size_t qBase = (size_t)bg*65536;        // == b*C*HW + g*64*HW
  for(int e=t;e<4096;e+=256){
    int d = e>>6, x = e&63;
    qT[d*65 + x] = qb[qBase + (size_t)d*HWPIX + i0 + x];
    kT[d*65 + x] = kb[(size_t)bg*4096 + e];
    vT[d*65 + x] = vb[(size_t)bg*4096 + e];
    bT[x*65 + d] = biasb[(size_t)bg*65536 + (size_t)d*1024 + i0 + x];  // d=j, x=il
  }
  __syncthreads();
  int lane = t&63, w = t>>6;
  int b = bg>>3, g = bg&7;
  for(int rr=0;rr<16;rr++){
    int il = w*16 + rr;
    int i = i0 + il;
    float qreg = qT[lane*65 + il];     // lane l holds q[i][d=l]
    float s0=0.f,s1=0.f,s2=0.f,s3=0.f;
    #pragma unroll 4
    for(int d=0;d<64;d+=4){
      s0 = fmaf(rdlane(qreg,d  ), kT[(d  )*65 + lane], s0);
      s1 = fmaf(rdlane(qreg,d+1), kT[(d+1)*65 + lane], s1);
      s2 = fmaf(rdlane(qreg,d+2), kT[(d+2)*65 + lane], s2);
      s3 = fmaf(rdlane(qreg,d+3), kT[(d+3)*65 + lane], s3);
    }
    float s = (s0+s1)+(s2+s3);
    s = s*SCALE + bT[il*65 + lane];
    float m = s;
    for(int msk=32;msk;msk>>=1) m = fmaxf(m, __shfl_xor(m, msk));
    float p = __expf(s - m);
    float l = p;
    for(int msk=32;msk;msk>>=1) l += __shfl_xor(l, msk);
    p = p / l;
    float o0=0.f,o1=0.f,o2=0.f,o3=0.f;
    #pragma unroll 4
    for(int j=0;j<64;j+=4){
      o0 = fmaf(rdlane(p,j  ), vT[lane*65 + j  ], o0);
      o1 = fmaf(rdlane(p,j+1), vT[lane*65 + j+1], o1);
      o2 = fmaf(rdlane(p,j+2), vT[lane*65 + j+2], o2);
      o3 = fmaf(rdlane(p,j+3), vT[lane*65 + j+3], o3);
    }
    obT[(size_t)b*524288 + (size_t)i*512 + g*64 + lane] = f2bf((o0+o1)+(o2+o3));
  }
}

extern "C" void kernel_launch(void* const* d_in, const int* in_sizes, int n_in,
                              void* d_out, int out_size, void* d_ws, size_t ws_size,
                              hipStream_t stream){
  const float* x    = (const float*)d_in[0];
  const float* n1g  = (const float*)d_in[1];
  const float* n1b  = (const float*)d_in[2];
  const float* n2g  = (const float*)d_in[3];
  const float* n2b  = (const float*)d_in[4];
  const float* qw   = (const float*)d_in[5];
  const float* kw   = (const float*)d_in[6];
  const float* vw   = (const float*)d_in[7];
  const float* dww  = (const float*)d_in[8];
  const float* dwb  = (const float*)d_in[9];
  const float* pww  = (const float*)d_in[10];
  const float* cw0  = (const float*)d_in[11];
  const float* cb0  = (const float*)d_in[12];
  const float* cw1  = (const float*)d_in[13];
  const float* cb1  = (const float*)d_in[14];
  const float* cw2  = (const float*)d_in[15];
  const float* cb2  = (const float*)d_in[16];
  const float* ow   = (const float*)d_in[17];
  const float* obb  = (const float*)d_in[18];
  const float* m1w  = (const float*)d_in[19];
  const float* m1bi = (const float*)d_in[20];
  const float* m2w  = (const float*)d_in[21];
  const float* m2bi = (const float*)d_in[22];
  float* out = (float*)d_out;          // reference output dtype is float32
  float* ws = (float*)d_ws;

  float* xn     = ws;                       // 1M f32: bn1 normalized (c-major, for sample)
  float* x2     = ws + 1048576;             // 1M f32: outproj out (res for mlp2, src for bn2)
  float* q      = ws + 2097152;             // 1M f32, dead after attn
  float* biasb  = ws + 3145728;             // 1M f32, dead after attn
  u16*   hT     = (u16*)(ws + 2097152);     // 4M u16 over dead {q,biasb}: mlp1 out [b][p][c2048]
  u16*   attnT  = (u16*)(ws + 4194304);     // 1M u16: attn out [b][p][c512]
  u16*   xnT    = (u16*)(ws + 4718592);     // 1M u16: bn1 T [bg][p][c64]; reused as bn2 T [b][p][c512]
  u16*   kvT    = (u16*)(ws + 5242880);     // 64K u16: [bg][p][c64]
  float* kbuf   = ws + 5275648;             // 64K f32
  float* vbuf   = ws + 5341184;             // 64K f32
  float* offg   = ws + 5406720;             // 64K f32 (aliased as bn stats when offg dead)
  float* bnAB   = offg;                     // 1024 f32 alias (disjoint lifetime)
  float* vgrid  = ws + 5472256;             // 2K f32
  u16*   wbf    = (u16*)(ws + 5474304);     // 2457600 u16 bf16 weights
  u16 *qwb = wbf, *kwb = wbf+32768, *vwb = wbf+65536, *owb = wbf+98304;
  u16 *m1wb = wbf+360448, *m2wb = wbf+1409024;

  cvtw_kernel<<<2400,256,0,stream>>>(qw,kw,vw,ow,m1w,m2w,wbf);
  bnstat_kernel<<<512,256,0,stream>>>(x, n1g, n1b, bnAB);
  bntrans_kernel<<<dim3(16,8,2),256,0,stream>>>(x, bnAB, xn, xnT, 0);
  gemm_lds<0><<<dim3(16,1,16),256,0,stream>>>(qwb, xnT, q, nullptr, nullptr, nullptr,
                                              64,64,1024, 7, 4096, 0);
  dwconv_kernel<<<256,256,0,stream>>>(q, dww, dwb, offg);
  pwgrid_kernel<<<16,64,0,stream>>>(offg, pww, vgrid);
  sample_kernel<<<16,256,0,stream>>>(xn, vgrid, kvT);
  gemm_lds<0><<<dim3(1,1,16),256,0,stream>>>(kwb, kvT, kbuf, nullptr, nullptr, nullptr,
                                             64,64,64, 7, 4096, 0);
  gemm_lds<0><<<dim3(1,1,16),256,0,stream>>>(vwb, kvT, vbuf, nullptr, nullptr, nullptr,
                                             64,64,64, 7, 4096, 0);
  biasmlp_kernel<<<1024,256,0,stream>>>(cw0, cb0, cw1, cb1, cw2, cb2, vgrid, biasb);
  attn_kernel<<<256,256,0,stream>>>(q, kbuf, vbuf, biasb, attnT);
  gemm_lds<0><<<dim3(16,8,2),256,0,stream>>>(owb, attnT, x2, nullptr, obb, x,
                                             512,512,1024, 0,0,0);
  bnstat_kernel<<<512,256,0,stream>>>(x2, n2g, n2b, bnAB);
  bntrans_kernel<<<dim3(16,8,2),256,0,stream>>>(x2, bnAB, nullptr, xnT, 1);
  gemm_lds<1><<<dim3(16,32,2),256,0,stream>>>(m1wb, xnT, nullptr, hT, m1bi, nullptr,
                                              2048,512,1024, 0,0,1);
  gemm_lds<0><<<dim3(16,8,2),256,0,stream>>>(m2wb, hT, out, nullptr, m2bi, x2,
                                             512,2048,1024, 0,0,0);
}

// Round 13
// 277.750 us; speedup vs baseline: 1.1012x; 1.0271x over previous
//
#include <hip/hip_runtime.h>
#include <cstdint>
#include <cstddef>

// ---- problem constants (B=2, C=512, H=W=32, G=8, Cg=64, h2=w2=8) ----
#define BATCH 2
#define CCH   512
#define HWPIX 1024           // 32*32
#define SCALE 0.125f         // 64^-0.5

typedef short bh8 __attribute__((ext_vector_type(8)));   // 8 x bf16 (4 VGPRs)
typedef _Float16 h8 __attribute__((ext_vector_type(8))); // 8 x fp16 (4 VGPRs)
typedef _Float16 h2 __attribute__((ext_vector_type(2))); // 2 x fp16 (1 VGPR)
typedef float f32x4 __attribute__((ext_vector_type(4)));
typedef unsigned short u16;
typedef u16 us8 __attribute__((ext_vector_type(8)));     // 16B of bf16
typedef u16 us4 __attribute__((ext_vector_type(4)));     // 8B of bf16

__device__ __forceinline__ u16 f2bf(float f){
  unsigned u = __float_as_uint(f);
  unsigned r = (u + 0x7FFFu + ((u>>16)&1u))>>16;   // RNE
  return (u16)r;
}
__device__ __forceinline__ float geluf(float v){ return 0.5f*v*(1.0f + erff(v*0.70710678118654752f)); }
__device__ __forceinline__ float rdlane(float v, int l){
  return __uint_as_float(__builtin_amdgcn_readlane(__float_as_uint(v), l));
}

// ---------------- weight preconvert: f32 -> bf16, 6 segments concatenated ----------------
__global__ __launch_bounds__(256) void cvtw_kernel(
    const float* __restrict__ qw, const float* __restrict__ kw, const float* __restrict__ vw,
    const float* __restrict__ ow, const float* __restrict__ m1, const float* __restrict__ m2,
    u16* __restrict__ dst){
  int idx = (blockIdx.x*256 + threadIdx.x)*4;
  if(idx >= 2457600) return;
  const float* src; int off;
  if(idx < 32768){ src=qw; off=idx; }
  else if(idx <   65536){ src=kw; off=idx-32768; }
  else if(idx <   98304){ src=vw; off=idx-65536; }
  else if(idx <  360448){ src=ow; off=idx-98304; }
  else if(idx < 1409024){ src=m1; off=idx-360448; }
  else                  { src=m2; off=idx-1409024; }
  float4 v = *(const float4*)&src[off];
  us4 r = (us4){f2bf(v.x), f2bf(v.y), f2bf(v.z), f2bf(v.w)};
  *(us4*)&dst[idx] = r;
}

// ---------------- BatchNorm stats: per-channel scale/shift -> AB[1024] ----------------
__global__ __launch_bounds__(256) void bnstat_kernel(const float* __restrict__ src,
      const float* __restrict__ g, const float* __restrict__ bta, float* __restrict__ AB){
  int c = blockIdx.x; int t = threadIdx.x;
  float s=0.f, ss=0.f;
  for(int b=0;b<BATCH;b++){
    size_t base = (size_t)b*CCH*HWPIX + (size_t)c*HWPIX;
    for(int p=t;p<HWPIX;p+=256){
      float v = src[base+p];
      s += v; ss += v*v;
    }
  }
  for(int o=32;o;o>>=1){ s += __shfl_down(s,o); ss += __shfl_down(ss,o); }
  __shared__ float ls[4], lss[4];
  int w = t>>6, lane = t&63;
  if(lane==0){ ls[w]=s; lss[w]=ss; }
  __syncthreads();
  if(t==0){
    float S=ls[0]+ls[1]+ls[2]+ls[3], SS=lss[0]+lss[1]+lss[2]+lss[3];
    float m = S*(1.0f/2048.0f);
    float var = SS*(1.0f/2048.0f) - m*m;
    float r = rsqrtf(var + 1e-5f);
    AB[c]     = r*g[c];
    AB[512+c] = bta[c] - m*r*g[c];
  }
}

// ---------------- BN apply + transpose: src [b][ch][p] f32 -> dstT [n][k] bf16 (+opt f32 copy) ----------------
// tMode 0: dstT[(b*8+g)*65536 + p*64 + c]  (grouped, K=64)   tMode 1: dstT[b*524288 + p*512 + g*64 + c]
__global__ __launch_bounds__(256) void bntrans_kernel(const float* __restrict__ src,
      const float* __restrict__ AB, float* __restrict__ dstF, u16* __restrict__ dstT, int tMode){
  __shared__ float tile[64*65];
  int t = threadIdx.x;
  int p0 = blockIdx.x*64, gq = blockIdx.y, b = blockIdx.z;
  int pl = t&63, seg = t>>6;
  #pragma unroll
  for(int r=0;r<16;r++){
    int c = seg*16 + r;
    int ch = gq*64 + c;
    size_t a = (size_t)b*524288 + (size_t)ch*1024 + p0 + pl;
    float v = src[a]*AB[ch] + AB[512+ch];
    tile[c*65 + pl] = v;
    if(dstF) dstF[a] = v;
  }
  __syncthreads();
  int c = t&63;
  #pragma unroll
  for(int r=0;r<16;r++){
    int p = seg*16 + r;
    float v = tile[c*65 + p];
    size_t a = tMode ? ((size_t)b*524288 + (size_t)(p0+p)*512 + gq*64 + c)
                     : ((size_t)(b*8+gq)*65536 + (size_t)(p0+p)*64 + c);
    dstT[a] = f2bf(v);
  }
}

// ------- LDS-staged pipelined GEMM: out[b][m][n] = W[m][k] @ Xt, Xt is [n][k] bf16 -------
// NT = 16-col n-subtiles per wave. Block tile = 64m x (64*NT)n. Write-side XOR swizzle
// kb'=kb^(row&7): conflict-free writes, 2-way-only reads. Register prefetch of next K-tile.
template<int NT, int TOUT>
__global__ __launch_bounds__(256,4) void gemm_lds(
    const u16* __restrict__ W, const u16* __restrict__ Xt,
    float* __restrict__ outF, u16* __restrict__ outT,
    const float* __restrict__ bias, const float* __restrict__ resF,
    int M, int K, int Nb, int wMask, int wStride, int doGelu){
  __shared__ __align__(16) u16 xS[64*NT*64];   // [row][kb' swizzled], 8*NT KB
  __shared__ __align__(16) u16 wS[64*64];      // 8KB
  int t = threadIdx.x;
  int w = t>>6, lane = t&63, l15 = lane&15, quad = lane>>4;
  int n0 = blockIdx.x*(64*NT), m0 = blockIdx.y*64, batch = blockIdx.z;
  const u16* Wg = W + (size_t)(batch & wMask)*wStride + (size_t)m0*K;
  const u16* Xg = Xt + (size_t)batch*Nb*K + (size_t)n0*K;
  // X staging: 2*NT chunks/thread; W staging: 2 chunks/thread
  const u16* pX[2*NT]; u16* sX[2*NT];
  #pragma unroll
  for(int p=0;p<2*NT;p++){
    int row = (p*256 + t)>>3, kb = t&7;
    pX[p] = Xg + (size_t)row*K + kb*8;
    sX[p] = &xS[(row*8 + (kb ^ (row&7)))*8];
  }
  int row0 = t>>3,        kb0 = t&7;
  int row1 = (256+t)>>3,  kb1 = t&7;
  const u16* pW0 = Wg + (size_t)row0*K + kb0*8;
  const u16* pW1 = Wg + (size_t)row1*K + kb1*8;
  u16* sW0 = &wS[(row0*8 + (kb0 ^ (row0&7)))*8];
  u16* sW1 = &wS[(row1*8 + (kb1 ^ (row1&7)))*8];
  f32x4 acc[4][NT];
  #pragma unroll
  for(int mt=0;mt<4;mt++)
    #pragma unroll
    for(int nt=0;nt<NT;nt++) acc[mt][nt] = (f32x4){0.f,0.f,0.f,0.f};
  us8 rx[2*NT], rw0, rw1;
  #pragma unroll
  for(int p=0;p<2*NT;p++) rx[p] = *(const us8*)pX[p];
  rw0 = *(const us8*)pW0; rw1 = *(const us8*)pW1;
  for(int kc=0;kc<K;kc+=64){
    #pragma unroll
    for(int p=0;p<2*NT;p++) *(us8*)sX[p] = rx[p];
    *(us8*)sW0 = rw0;  *(us8*)sW1 = rw1;
    __syncthreads();
    if(kc+64 < K){
      #pragma unroll
      for(int p=0;p<2*NT;p++) rx[p] = *(const us8*)(pX[p] + kc+64);
      rw0 = *(const us8*)(pW0 + kc+64);  rw1 = *(const us8*)(pW1 + kc+64);
    }
    #pragma unroll
    for(int ks=0;ks<2;ks++){
      bh8 bF[NT];
      #pragma unroll
      for(int nt=0;nt<NT;nt++){
        int rb = (w*NT + nt)*16 + l15;
        bF[nt] = *(const bh8*)&xS[rb*64 + ((ks*4+quad) ^ (rb&7))*8];
      }
      #pragma unroll
      for(int mt=0;mt<4;mt++){
        int ra = mt*16 + l15;
        bh8 aF = *(const bh8*)&wS[ra*64 + ((ks*4+quad) ^ (ra&7))*8];
        #pragma unroll
        for(int nt=0;nt<NT;nt++)
          acc[mt][nt] = __builtin_amdgcn_mfma_f32_16x16x32_bf16(aF, bF[nt], acc[mt][nt], 0,0,0);
      }
    }
    __syncthreads();
  }
  if(TOUT){
    size_t oB = (size_t)batch*Nb*(size_t)M;
    #pragma unroll
    for(int nt=0;nt<NT;nt++){
      int n = n0 + (w*NT + nt)*16 + l15;
      #pragma unroll
      for(int mt=0;mt<4;mt++){
        int m = m0 + mt*16 + quad*4;
        us4 pk;
        #pragma unroll
        for(int reg=0;reg<4;reg++){
          float v = acc[mt][nt][reg];
          if(bias) v += bias[m+reg];
          if(doGelu) v = geluf(v);
          pk[reg] = f2bf(v);
        }
        *(us4*)&outT[oB + (size_t)n*M + m] = pk;
      }
    }
  } else {
    size_t oB = (size_t)batch*(size_t)M*Nb;
    #pragma unroll
    for(int nt=0;nt<NT;nt++){
      int n = n0 + (w*NT + nt)*16 + l15;
      #pragma unroll
      for(int mt=0;mt<4;mt++)
        #pragma unroll
        for(int reg=0;reg<4;reg++){
          int m = m0 + mt*16 + quad*4 + reg;      // C/D: col=lane&15, row=quad*4+reg
          float v = acc[mt][nt][reg];
          if(bias) v += bias[m];
          if(doGelu) v = geluf(v);
          size_t a = oB + (size_t)m*Nb + n;
          if(resF) v += resF[a];
          outF[a] = v;
        }
    }
  }
}

// ------------- depthwise 6x6 stride-4 pad-1 conv + exact gelu -------------
__global__ __launch_bounds__(256) void dwconv_kernel(const float* __restrict__ q,
    const float* __restrict__ dw, const float* __restrict__ dwb, float* __restrict__ offg){
  int t = threadIdx.x;
  int bgc = blockIdx.x*4 + (t>>6);       // 0..1023 = bg*64 + c
  int c = bgc & 63;
  int pix = t&63;
  int oy = pix>>3, ox = pix&7;
  const float* img = q + (size_t)bgc*HWPIX;
  float acc = dwb[c];
  #pragma unroll
  for(int ky=0;ky<6;ky++){
    int y = oy*4 - 1 + ky;
    if(y<0 || y>31) continue;
    #pragma unroll
    for(int kx=0;kx<6;kx++){
      int x = ox*4 - 1 + kx;
      if(x<0 || x>31) continue;
      acc = fmaf(img[y*32 + x], dw[c*36 + ky*6 + kx], acc);
    }
  }
  offg[(size_t)bgc*64 + pix] = geluf(acc);
}

// ------------- pointwise 64->2, tanh*4, build sampling grid -------------
__global__ __launch_bounds__(64) void pwgrid_kernel(const float* __restrict__ offg,
    const float* __restrict__ pw, float* __restrict__ vgrid){
  int bg = blockIdx.x; int p = threadIdx.x;
  float a0=0.f, a1=0.f;
  for(int c=0;c<64;c++){
    float v = offg[(size_t)bg*4096 + c*64 + p];
    a0 = fmaf(v, pw[c], a0);
    a1 = fmaf(v, pw[64+c], a1);
  }
  float o0 = tanhf(a0)*4.0f, o1 = tanhf(a1)*4.0f;
  float gx = (float)(p&7), gy = (float)(p>>3);
  float vxx = (2.0f/7.0f)*(gx + o0) - 1.0f;
  float vyy = (2.0f/7.0f)*(gy + o1) - 1.0f;
  vgrid[bg*128 + p*2]     = vxx;
  vgrid[bg*128 + p*2 + 1] = vyy;
}

// ------------- bilinear grid sample (zero padding), bf16 [p][c] output -------------
// grid (16 bg, 4 cgroup): 64 blocks (was 16 — 6% GPU util was leaving latency exposed)
__device__ __forceinline__ float fetchpix(const float* img, int ix, int iy){
  return (ix>=0 && ix<32 && iy>=0 && iy<32) ? img[iy*32+ix] : 0.0f;
}
__global__ __launch_bounds__(256) void sample_kernel(const float* __restrict__ xn,
    const float* __restrict__ vgrid, u16* __restrict__ kvT){
  int bg = blockIdx.x; int t = threadIdx.x;
  int p = t&63, cblk = t>>6;
  int cbase = blockIdx.y*16 + cblk*4;
  float vx = vgrid[bg*128 + p*2], vy = vgrid[bg*128 + p*2+1];
  float xs = ((vx + 1.0f)*32.0f - 1.0f)*0.5f;
  float ys = ((vy + 1.0f)*32.0f - 1.0f)*0.5f;
  float x0 = floorf(xs), y0 = floorf(ys);
  float wx = xs - x0, wy = ys - y0;
  int ix0 = (int)x0, iy0 = (int)y0;
  int b = bg>>3, g = bg&7;
  float w00 = (1.f-wx)*(1.f-wy), w10 = wx*(1.f-wy), w01 = (1.f-wx)*wy, w11 = wx*wy;
  us4 tmp;
  #pragma unroll
  for(int cc=0;cc<4;cc++){
    int c = cbase + cc;
    const float* img = xn + (size_t)b*CCH*HWPIX + (size_t)(g*64+c)*HWPIX;
    float acc = w00*fetchpix(img,ix0,iy0)   + w10*fetchpix(img,ix0+1,iy0)
              + w01*fetchpix(img,ix0,iy0+1) + w11*fetchpix(img,ix0+1,iy0+1);
    tmp[cc] = f2bf(acc);
  }
  *(us4*)&kvT[(size_t)bg*4096 + p*64 + cbase] = tmp;
}

// ------------- CPB bias MLP (R9 proven body, 52.3 µs): packed-f16 layer-0, f16 MFMA layer-1 -------------
// (256,2) proven best (R11: removing it -> 144 VGPR, occupancy 10%, 72 µs). Output: biasOut[bg][j][i]
__global__ __launch_bounds__(256,2) void biasmlp_kernel(
    const float* __restrict__ w0, const float* __restrict__ b0,
    const float* __restrict__ w1, const float* __restrict__ b1,
    const float* __restrict__ w2, const float* __restrict__ b2,
    const float* __restrict__ vgrid, float* __restrict__ biasOut){
  __shared__ __align__(16) _Float16 w1h[128*136];   // W1 transposed: [n][k] f16
  int t = threadIdx.x;
  int bg = blockIdx.x >> 6, jj = blockIdx.x & 63;
  for(int e=t;e<16384;e+=256){
    int k = e>>7, n = e&127;
    w1h[n*136 + k] = (_Float16)w1[e];             // w1 is [k][n] row-major f32
  }
  float vx = vgrid[bg*128 + jj*2];
  float vy = vgrid[bg*128 + jj*2 + 1];
  int lane = t&63, w = t>>6, l15 = lane&15, quad = lane>>4;
  int gxi = (w*16 + l15)&31;
  float px = (2.0f/31.0f)*(float)gxi - 1.0f - vx;
  float u = copysignf(__logf(1.0f + fabsf(px)), px);
  h2 t1p[16], wyp[16];
  #pragma unroll
  for(int ks=0;ks<4;ks++){
    #pragma unroll
    for(int d=0;d<4;d++){
      int k = ks*32 + quad*8 + 2*d;
      t1p[ks*4+d] = (h2){(_Float16)fmaf(u, w0[k], b0[k]), (_Float16)fmaf(u, w0[k+1], b0[k+1])};
      wyp[ks*4+d] = (h2){(_Float16)w0[128+k], (_Float16)w0[128+k+1]};
    }
  }
  __syncthreads();
  h8 bfr[8][4];
  float b1f[8], w2f[8];
  #pragma unroll
  for(int nt=0;nt<8;nt++){
    int n = nt*16 + l15;
    b1f[nt] = b1[n];
    w2f[nt] = w2[n];
    #pragma unroll
    for(int ks=0;ks<4;ks++)
      bfr[nt][ks] = *(const h8*)&w1h[n*136 + ks*32 + quad*8];
  }
  float b2v = b2[0];
  const h2 z2 = (h2){(_Float16)0.f, (_Float16)0.f};
  float* outP = biasOut + (size_t)bg*65536 + (size_t)jj*1024;
  for(int s=0;s<16;s++){
    int gyi = (s*64 + w*16 + l15)>>5;
    float py = (2.0f/31.0f)*(float)gyi - 1.0f - vy;
    float v = copysignf(__logf(1.0f + fabsf(py)), py);
    _Float16 vh = (_Float16)v;
    h2 v2 = (h2){vh, vh};
    union { h2 p[4]; h8 v8; } ah[4];
    #pragma unroll
    for(int ks=0;ks<4;ks++){
      #pragma unroll
      for(int d=0;d<4;d++)
        ah[ks].p[d] = __builtin_elementwise_max(v2*wyp[ks*4+d] + t1p[ks*4+d], z2);
    }
    f32x4 acc[8];
    #pragma unroll
    for(int nt=0;nt<8;nt++)
      acc[nt] = (f32x4){b1f[nt], b1f[nt], b1f[nt], b1f[nt]};
    #pragma unroll
    for(int ks=0;ks<4;ks++){
      #pragma unroll
      for(int nt=0;nt<8;nt++)
        acc[nt] = __builtin_amdgcn_mfma_f32_16x16x32_f16(ah[ks].v8, bfr[nt][ks], acc[nt],0,0,0);
    }
    float pr[4];
    #pragma unroll
    for(int reg=0;reg<4;reg++){
      float p = 0.f;
      #pragma unroll
      for(int nt=0;nt<8;nt++)
        p = fmaf(fmaxf(acc[nt][reg], 0.0f), w2f[nt], p);
      p += __shfl_xor(p, 1);
      p += __shfl_xor(p, 2);
      p += __shfl_xor(p, 4);
      p += __shfl_xor(p, 8);
      pr[reg] = p + b2v;
    }
    if(l15==0){
      *(f32x4*)&outP[s*64 + w*16 + quad*4] = (f32x4){pr[0], pr[1], pr[2], pr[3]};
    }
  }
}

// ------------- attention: softmax(q·K*scale + bias) @ V, output [b][p][ch] bf16 -------------
__global__ __launch_bounds__(256) void attn_kernel(
    const float* __restrict__ qb, const float* __restrict__ kb, const float* __restrict__ vb,
    const float* __restrict__ biasb, u16* __restrict__ obT){
  __shared__ float qT[64*65], kT[64*65], vT[64*65], bT[64*65];
  int t = threadIdx.x;
  int bg = blockIdx.x>>4, itile = blockIdx.x&15;
  int i0 = itile*64;
  size_t qBase = (size_t)bg*65536;        // == b*C*HW + g*64*HW
  for(int e=t;e<4096;e+=256){
    int d = e>>6, x = e&63;
    qT[d*65 + x] = qb[qBase + (size_t)d*HWPIX + i0 + x];
    kT[d*65 + x] = kb[(size_t)bg*4096 + e];
    vT[d*65 + x] = vb[(size_t)bg*4096 + e];
    bT[x*65 + d] = biasb[(size_t)bg*65536 + (size_t)d*1024 + i0 + x];  // d=j, x=il
  }
  __syncthreads();
  int lane = t&63, w = t>>6;
  int b = bg>>3, g = bg&7;
  for(int rr=0;rr<16;rr++){
    int il = w*16 + rr;
    int i = i0 + il;
    float qreg = qT[lane*65 + il];     // lane l holds q[i][d=l]
    float s0=0.f,s1=0.f,s2=0.f,s3=0.f;
    #pragma unroll 4
    for(int d=0;d<64;d+=4){
      s0 = fmaf(rdlane(qreg,d  ), kT[(d  )*65 + lane], s0);
      s1 = fmaf(rdlane(qreg,d+1), kT[(d+1)*65 + lane], s1);
      s2 = fmaf(rdlane(qreg,d+2), kT[(d+2)*65 + lane], s2);
      s3 = fmaf(rdlane(qreg,d+3), kT[(d+3)*65 + lane], s3);
    }
    float s = (s0+s1)+(s2+s3);
    s = s*SCALE + bT[il*65 + lane];
    float m = s;
    for(int msk=32;msk;msk>>=1) m = fmaxf(m, __shfl_xor(m, msk));
    float p = __expf(s - m);
    float l = p;
    for(int msk=32;msk;msk>>=1) l += __shfl_xor(l, msk);
    p = p / l;
    float o0=0.f,o1=0.f,o2=0.f,o3=0.f;
    #pragma unroll 4
    for(int j=0;j<64;j+=4){
      o0 = fmaf(rdlane(p,j  ), vT[lane*65 + j  ], o0);
      o1 = fmaf(rdlane(p,j+1), vT[lane*65 + j+1], o1);
      o2 = fmaf(rdlane(p,j+2), vT[lane*65 + j+2], o2);
      o3 = fmaf(rdlane(p,j+3), vT[lane*65 + j+3], o3);
    }
    obT[(size_t)b*524288 + (size_t)i*512 + g*64 + lane] = f2bf((o0+o1)+(o2+o3));
  }
}

extern "C" void kernel_launch(void* const* d_in, const int* in_sizes, int n_in,
                              void* d_out, int out_size, void* d_ws, size_t ws_size,
                              hipStream_t stream){
  const float* x    = (const float*)d_in[0];
  const float* n1g  = (const float*)d_in[1];
  const float* n1b  = (const float*)d_in[2];
  const float* n2g  = (const float*)d_in[3];
  const float* n2b  = (const float*)d_in[4];
  const float* qw   = (const float*)d_in[5];
  const float* kw   = (const float*)d_in[6];
  const float* vw   = (const float*)d_in[7];
  const float* dww  = (const float*)d_in[8];
  const float* dwb  = (const float*)d_in[9];
  const float* pww  = (const float*)d_in[10];
  const float* cw0  = (const float*)d_in[11];
  const float* cb0  = (const float*)d_in[12];
  const float* cw1  = (const float*)d_in[13];
  const float* cb1  = (const float*)d_in[14];
  const float* cw2  = (const float*)d_in[15];
  const float* cb2  = (const float*)d_in[16];
  const float* ow   = (const float*)d_in[17];
  const float* obb  = (const float*)d_in[18];
  const float* m1w  = (const float*)d_in[19];
  const float* m1bi = (const float*)d_in[20];
  const float* m2w  = (const float*)d_in[21];
  const float* m2bi = (const float*)d_in[22];
  float* out = (float*)d_out;          // reference output dtype is float32
  float* ws = (float*)d_ws;

  float* xn     = ws;                       // 1M f32: bn1 normalized (c-major, for sample)
  float* x2     = ws + 1048576;             // 1M f32: outproj out (res for mlp2, src for bn2)
  float* q      = ws + 2097152;             // 1M f32, dead after attn
  float* biasb  = ws + 3145728;             // 1M f32, dead after attn
  u16*   hT     = (u16*)(ws + 2097152);     // 4M u16 over dead {q,biasb}: mlp1 out [b][p][c2048]
  u16*   attnT  = (u16*)(ws + 4194304);     // 1M u16: attn out [b][p][c512]
  u16*   xnT    = (u16*)(ws + 4718592);     // 1M u16: bn1 T [bg][p][c64]; reused as bn2 T [b][p][c512]
  u16*   kvT    = (u16*)(ws + 5242880);     // 64K u16: [bg][p][c64]
  float* kbuf   = ws + 5275648;             // 64K f32
  float* vbuf   = ws + 5341184;             // 64K f32
  float* offg   = ws + 5406720;             // 64K f32 (aliased as bn stats when offg dead)
  float* bnAB   = offg;                     // 1024 f32 alias (disjoint lifetime)
  float* vgrid  = ws + 5472256;             // 2K f32
  u16*   wbf    = (u16*)(ws + 5474304);     // 2457600 u16 bf16 weights
  u16 *qwb = wbf, *kwb = wbf+32768, *vwb = wbf+65536, *owb = wbf+98304;
  u16 *m1wb = wbf+360448, *m2wb = wbf+1409024;

  cvtw_kernel<<<2400,256,0,stream>>>(qw,kw,vw,ow,m1w,m2w,wbf);
  bnstat_kernel<<<512,256,0,stream>>>(x, n1g, n1b, bnAB);
  bntrans_kernel<<<dim3(16,8,2),256,0,stream>>>(x, bnAB, xn, xnT, 0);
  gemm_lds<1,0><<<dim3(16,1,16),256,0,stream>>>(qwb, xnT, q, nullptr, nullptr, nullptr,
                                                64,64,1024, 7, 4096, 0);
  dwconv_kernel<<<256,256,0,stream>>>(q, dww, dwb, offg);
  pwgrid_kernel<<<16,64,0,stream>>>(offg, pww, vgrid);
  sample_kernel<<<dim3(16,4),256,0,stream>>>(xn, vgrid, kvT);
  gemm_lds<1,0><<<dim3(1,1,16),256,0,stream>>>(kwb, kvT, kbuf, nullptr, nullptr, nullptr,
                                               64,64,64, 7, 4096, 0);
  gemm_lds<1,0><<<dim3(1,1,16),256,0,stream>>>(vwb, kvT, vbuf, nullptr, nullptr, nullptr,
                                               64,64,64, 7, 4096, 0);
  biasmlp_kernel<<<1024,256,0,stream>>>(cw0, cb0, cw1, cb1, cw2, cb2, vgrid, biasb);
  attn_kernel<<<256,256,0,stream>>>(q, kbuf, vbuf, biasb, attnT);
  gemm_lds<1,0><<<dim3(16,8,2),256,0,stream>>>(owb, attnT, x2, nullptr, obb, x,
                                               512,512,1024, 0,0,0);
  bnstat_kernel<<<512,256,0,stream>>>(x2, n2g, n2b, bnAB);
  bntrans_kernel<<<dim3(16,8,2),256,0,stream>>>(x2, bnAB, nullptr, xnT, 1);
  // mlp1: NT=2 (64m x 128n tile, 16 MFMA per wave per k-iter), grid 512 blocks
  gemm_lds<2,1><<<dim3(8,32,2),256,0,stream>>>(m1wb, xnT, nullptr, hT, m1bi, nullptr,
                                               2048,512,1024, 0,0,1);
  gemm_lds<1,0><<<dim3(16,8,2),256,0,stream>>>(m2wb, hT, out, nullptr, m2bi, x2,
                                               512,2048,1024, 0,0,0);
}

// Round 14
// 250.078 us; speedup vs baseline: 1.2231x; 1.1107x over previous
//
#include <hip/hip_runtime.h>
#include <cstdint>
#include <cstddef>

// ---- problem constants (B=2, C=512, H=W=32, G=8, Cg=64, h2=w2=8) ----
#define BATCH 2
#define CCH   512
#define HWPIX 1024           // 32*32
#define SCALE 0.125f         // 64^-0.5
// CPB bias lookup table: F(u,v) on 64x64 grid over [-1.45,1.45]^2.
// |u|,|v| <= log1p(3.143) = 1.422 < 1.45 (|tanh|<1 bound). F is piecewise-linear
// (relu MLP) -> bilinear interp error ~1e-6 absolute (kink slope-step ~5e-5 x dx/4).
#define TU0  (-1.45f)
#define TDU  (2.9f/63.0f)
#define TINV (63.0f/2.9f)

typedef short bh8 __attribute__((ext_vector_type(8)));   // 8 x bf16 (4 VGPRs)
typedef float f32x4 __attribute__((ext_vector_type(4)));
typedef unsigned short u16;
typedef u16 us8 __attribute__((ext_vector_type(8)));     // 16B of bf16
typedef u16 us4 __attribute__((ext_vector_type(4)));     // 8B of bf16

__device__ __forceinline__ u16 f2bf(float f){
  unsigned u = __float_as_uint(f);
  unsigned r = (u + 0x7FFFu + ((u>>16)&1u))>>16;   // RNE
  return (u16)r;
}
__device__ __forceinline__ float geluf(float v){ return 0.5f*v*(1.0f + erff(v*0.70710678118654752f)); }
__device__ __forceinline__ float rdlane(float v, int l){
  return __uint_as_float(__builtin_amdgcn_readlane(__float_as_uint(v), l));
}

// ---------------- weight preconvert: f32 -> bf16, 6 segments concatenated ----------------
__global__ __launch_bounds__(256) void cvtw_kernel(
    const float* __restrict__ qw, const float* __restrict__ kw, const float* __restrict__ vw,
    const float* __restrict__ ow, const float* __restrict__ m1, const float* __restrict__ m2,
    u16* __restrict__ dst){
  int idx = (blockIdx.x*256 + threadIdx.x)*4;
  if(idx >= 2457600) return;
  const float* src; int off;
  if(idx < 32768){ src=qw; off=idx; }
  else if(idx <   65536){ src=kw; off=idx-32768; }
  else if(idx <   98304){ src=vw; off=idx-65536; }
  else if(idx <  360448){ src=ow; off=idx-98304; }
  else if(idx < 1409024){ src=m1; off=idx-360448; }
  else                  { src=m2; off=idx-1409024; }
  float4 v = *(const float4*)&src[off];
  us4 r = (us4){f2bf(v.x), f2bf(v.y), f2bf(v.z), f2bf(v.w)};
  *(us4*)&dst[idx] = r;
}

// ---------------- BatchNorm stats: per-channel scale/shift -> AB[1024] ----------------
__global__ __launch_bounds__(256) void bnstat_kernel(const float* __restrict__ src,
      const float* __restrict__ g, const float* __restrict__ bta, float* __restrict__ AB){
  int c = blockIdx.x; int t = threadIdx.x;
  float s=0.f, ss=0.f;
  for(int b=0;b<BATCH;b++){
    size_t base = (size_t)b*CCH*HWPIX + (size_t)c*HWPIX;
    for(int p=t;p<HWPIX;p+=256){
      float v = src[base+p];
      s += v; ss += v*v;
    }
  }
  for(int o=32;o;o>>=1){ s += __shfl_down(s,o); ss += __shfl_down(ss,o); }
  __shared__ float ls[4], lss[4];
  int w = t>>6, lane = t&63;
  if(lane==0){ ls[w]=s; lss[w]=ss; }
  __syncthreads();
  if(t==0){
    float S=ls[0]+ls[1]+ls[2]+ls[3], SS=lss[0]+lss[1]+lss[2]+lss[3];
    float m = S*(1.0f/2048.0f);
    float var = SS*(1.0f/2048.0f) - m*m;
    float r = rsqrtf(var + 1e-5f);
    AB[c]     = r*g[c];
    AB[512+c] = bta[c] - m*r*g[c];
  }
}

// ---------------- BN apply + transpose: src [b][ch][p] f32 -> dstT [n][k] bf16 (+opt f32 copy) ----------------
// tMode 0: dstT[(b*8+g)*65536 + p*64 + c]  (grouped, K=64)   tMode 1: dstT[b*524288 + p*512 + g*64 + c]
__global__ __launch_bounds__(256) void bntrans_kernel(const float* __restrict__ src,
      const float* __restrict__ AB, float* __restrict__ dstF, u16* __restrict__ dstT, int tMode){
  __shared__ float tile[64*65];
  int t = threadIdx.x;
  int p0 = blockIdx.x*64, gq = blockIdx.y, b = blockIdx.z;
  int pl = t&63, seg = t>>6;
  #pragma unroll
  for(int r=0;r<16;r++){
    int c = seg*16 + r;
    int ch = gq*64 + c;
    size_t a = (size_t)b*524288 + (size_t)ch*1024 + p0 + pl;
    float v = src[a]*AB[ch] + AB[512+ch];
    tile[c*65 + pl] = v;
    if(dstF) dstF[a] = v;
  }
  __syncthreads();
  int c = t&63;
  #pragma unroll
  for(int r=0;r<16;r++){
    int p = seg*16 + r;
    float v = tile[c*65 + p];
    size_t a = tMode ? ((size_t)b*524288 + (size_t)(p0+p)*512 + gq*64 + c)
                     : ((size_t)(b*8+gq)*65536 + (size_t)(p0+p)*64 + c);
    dstT[a] = f2bf(v);
  }
}

// ------- LDS-staged pipelined GEMM: out[b][m][n] = W[m][k] @ Xt, Xt is [n][k] bf16 -------
// NT = 16-col n-subtiles per wave. Block tile = 64m x (64*NT)n. Write-side XOR swizzle
// kb'=kb^(row&7): conflict-free writes, 2-way-only reads. Register prefetch of next K-tile.
template<int NT, int TOUT>
__global__ __launch_bounds__(256,4) void gemm_lds(
    const u16* __restrict__ W, const u16* __restrict__ Xt,
    float* __restrict__ outF, u16* __restrict__ outT,
    const float* __restrict__ bias, const float* __restrict__ resF,
    int M, int K, int Nb, int wMask, int wStride, int doGelu){
  __shared__ __align__(16) u16 xS[64*NT*64];   // [row][kb' swizzled], 8*NT KB
  __shared__ __align__(16) u16 wS[64*64];      // 8KB
  int t = threadIdx.x;
  int w = t>>6, lane = t&63, l15 = lane&15, quad = lane>>4;
  int n0 = blockIdx.x*(64*NT), m0 = blockIdx.y*64, batch = blockIdx.z;
  const u16* Wg = W + (size_t)(batch & wMask)*wStride + (size_t)m0*K;
  const u16* Xg = Xt + (size_t)batch*Nb*K + (size_t)n0*K;
  // X staging: 2*NT chunks/thread; W staging: 2 chunks/thread
  const u16* pX[2*NT]; u16* sX[2*NT];
  #pragma unroll
  for(int p=0;p<2*NT;p++){
    int row = (p*256 + t)>>3, kb = t&7;
    pX[p] = Xg + (size_t)row*K + kb*8;
    sX[p] = &xS[(row*8 + (kb ^ (row&7)))*8];
  }
  int row0 = t>>3,        kb0 = t&7;
  int row1 = (256+t)>>3,  kb1 = t&7;
  const u16* pW0 = Wg + (size_t)row0*K + kb0*8;
  const u16* pW1 = Wg + (size_t)row1*K + kb1*8;
  u16* sW0 = &wS[(row0*8 + (kb0 ^ (row0&7)))*8];
  u16* sW1 = &wS[(row1*8 + (kb1 ^ (row1&7)))*8];
  f32x4 acc[4][NT];
  #pragma unroll
  for(int mt=0;mt<4;mt++)
    #pragma unroll
    for(int nt=0;nt<NT;nt++) acc[mt][nt] = (f32x4){0.f,0.f,0.f,0.f};
  us8 rx[2*NT], rw0, rw1;
  #pragma unroll
  for(int p=0;p<2*NT;p++) rx[p] = *(const us8*)pX[p];
  rw0 = *(const us8*)pW0; rw1 = *(const us8*)pW1;
  for(int kc=0;kc<K;kc+=64){
    #pragma unroll
    for(int p=0;p<2*NT;p++) *(us8*)sX[p] = rx[p];
    *(us8*)sW0 = rw0;  *(us8*)sW1 = rw1;
    __syncthreads();
    if(kc+64 < K){
      #pragma unroll
      for(int p=0;p<2*NT;p++) rx[p] = *(const us8*)(pX[p] + kc+64);
      rw0 = *(const us8*)(pW0 + kc+64);  rw1 = *(const us8*)(pW1 + kc+64);
    }
    #pragma unroll
    for(int ks=0;ks<2;ks++){
      bh8 bF[NT];
      #pragma unroll
      for(int nt=0;nt<NT;nt++){
        int rb = (w*NT + nt)*16 + l15;
        bF[nt] = *(const bh8*)&xS[rb*64 + ((ks*4+quad) ^ (rb&7))*8];
      }
      #pragma unroll
      for(int mt=0;mt<4;mt++){
        int ra = mt*16 + l15;
        bh8 aF = *(const bh8*)&wS[ra*64 + ((ks*4+quad) ^ (ra&7))*8];
        #pragma unroll
        for(int nt=0;nt<NT;nt++)
          acc[mt][nt] = __builtin_amdgcn_mfma_f32_16x16x32_bf16(aF, bF[nt], acc[mt][nt], 0,0,0);
      }
    }
    __syncthreads();
  }
  if(TOUT){
    size_t oB = (size_t)batch*Nb*(size_t)M;
    #pragma unroll
    for(int nt=0;nt<NT;nt++){
      int n = n0 + (w*NT + nt)*16 + l15;
      #pragma unroll
      for(int mt=0;mt<4;mt++){
        int m = m0 + mt*16 + quad*4;
        us4 pk;
        #pragma unroll
        for(int reg=0;reg<4;reg++){
          float v = acc[mt][nt][reg];
          if(bias) v += bias[m+reg];
          if(doGelu) v = geluf(v);
          pk[reg] = f2bf(v);
        }
        *(us4*)&outT[oB + (size_t)n*M + m] = pk;
      }
    }
  } else {
    size_t oB = (size_t)batch*(size_t)M*Nb;
    #pragma unroll
    for(int nt=0;nt<NT;nt++){
      int n = n0 + (w*NT + nt)*16 + l15;
      #pragma unroll
      for(int mt=0;mt<4;mt++)
        #pragma unroll
        for(int reg=0;reg<4;reg++){
          int m = m0 + mt*16 + quad*4 + reg;      // C/D: col=lane&15, row=quad*4+reg
          float v = acc[mt][nt][reg];
          if(bias) v += bias[m];
          if(doGelu) v = geluf(v);
          size_t a = oB + (size_t)m*Nb + n;
          if(resF) v += resF[a];
          outF[a] = v;
        }
    }
  }
}

// ------------- depthwise 6x6 stride-4 pad-1 conv + exact gelu -------------
__global__ __launch_bounds__(256) void dwconv_kernel(const float* __restrict__ q,
    const float* __restrict__ dw, const float* __restrict__ dwb, float* __restrict__ offg){
  int t = threadIdx.x;
  int bgc = blockIdx.x*4 + (t>>6);       // 0..1023 = bg*64 + c
  int c = bgc & 63;
  int pix = t&63;
  int oy = pix>>3, ox = pix&7;
  const float* img = q + (size_t)bgc*HWPIX;
  float acc = dwb[c];
  #pragma unroll
  for(int ky=0;ky<6;ky++){
    int y = oy*4 - 1 + ky;
    if(y<0 || y>31) continue;
    #pragma unroll
    for(int kx=0;kx<6;kx++){
      int x = ox*4 - 1 + kx;
      if(x<0 || x>31) continue;
      acc = fmaf(img[y*32 + x], dw[c*36 + ky*6 + kx], acc);
    }
  }
  offg[(size_t)bgc*64 + pix] = geluf(acc);
}

// ------------- pointwise 64->2, tanh*4, build sampling grid -------------
__global__ __launch_bounds__(64) void pwgrid_kernel(const float* __restrict__ offg,
    const float* __restrict__ pw, float* __restrict__ vgrid){
  int bg = blockIdx.x; int p = threadIdx.x;
  float a0=0.f, a1=0.f;
  for(int c=0;c<64;c++){
    float v = offg[(size_t)bg*4096 + c*64 + p];
    a0 = fmaf(v, pw[c], a0);
    a1 = fmaf(v, pw[64+c], a1);
  }
  float o0 = tanhf(a0)*4.0f, o1 = tanhf(a1)*4.0f;
  float gx = (float)(p&7), gy = (float)(p>>3);
  float vxx = (2.0f/7.0f)*(gx + o0) - 1.0f;
  float vyy = (2.0f/7.0f)*(gy + o1) - 1.0f;
  vgrid[bg*128 + p*2]     = vxx;
  vgrid[bg*128 + p*2 + 1] = vyy;
}

// ------------- bilinear grid sample (zero padding), bf16 [p][c] output -------------
__device__ __forceinline__ float fetchpix(const float* img, int ix, int iy){
  return (ix>=0 && ix<32 && iy>=0 && iy<32) ? img[iy*32+ix] : 0.0f;
}
__global__ __launch_bounds__(256) void sample_kernel(const float* __restrict__ xn,
    const float* __restrict__ vgrid, u16* __restrict__ kvT){
  int bg = blockIdx.x; int t = threadIdx.x;
  int p = t&63, cblk = t>>6;
  int cbase = blockIdx.y*16 + cblk*4;
  float vx = vgrid[bg*128 + p*2], vy = vgrid[bg*128 + p*2+1];
  float xs = ((vx + 1.0f)*32.0f - 1.0f)*0.5f;
  float ys = ((vy + 1.0f)*32.0f - 1.0f)*0.5f;
  float x0 = floorf(xs), y0 = floorf(ys);
  float wx = xs - x0, wy = ys - y0;
  int ix0 = (int)x0, iy0 = (int)y0;
  int b = bg>>3, g = bg&7;
  float w00 = (1.f-wx)*(1.f-wy), w10 = wx*(1.f-wy), w01 = (1.f-wx)*wy, w11 = wx*wy;
  us4 tmp;
  #pragma unroll
  for(int cc=0;cc<4;cc++){
    int c = cbase + cc;
    const float* img = xn + (size_t)b*CCH*HWPIX + (size_t)(g*64+c)*HWPIX;
    float acc = w00*fetchpix(img,ix0,iy0)   + w10*fetchpix(img,ix0+1,iy0)
              + w01*fetchpix(img,ix0,iy0+1) + w11*fetchpix(img,ix0+1,iy0+1);
    tmp[cc] = f2bf(acc);
  }
  *(us4*)&kvT[(size_t)bg*4096 + p*64 + cbase] = tmp;
}

// ------------- CPB table build: F(u,v) = MLP(u,v) on 64x64 grid -------------
// 256 blocks x 256 threads: 16 entries x 16 n-chunks(8) per block; LDS reduce.
__global__ __launch_bounds__(256) void tabbuild_kernel(
    const float* __restrict__ w0, const float* __restrict__ b0,
    const float* __restrict__ w1, const float* __restrict__ b1,
    const float* __restrict__ w2, const float* __restrict__ b2,
    float* __restrict__ tab){
  int t = threadIdx.x;
  int eloc = t & 15, chunk = t >> 4;           // 16 entries x 16 chunks of 8 n
  int e = blockIdx.x*16 + eloc;                // 0..4095
  int iu = e & 63, iv = e >> 6;
  float u = TU0 + iu*TDU, v = TU0 + iv*TDU;
  float acc[8] = {0.f,0.f,0.f,0.f,0.f,0.f,0.f,0.f};
  for(int k=0;k<128;k++){
    float h0 = fmaxf(fmaf(u, w0[k], fmaf(v, w0[128+k], b0[k])), 0.f);
    const float* wr = &w1[k*128 + chunk*8];
    #pragma unroll
    for(int n=0;n<8;n++) acc[n] = fmaf(h0, wr[n], acc[n]);
  }
  float partial = 0.f;
  #pragma unroll
  for(int n=0;n<8;n++)
    partial = fmaf(fmaxf(acc[n] + b1[chunk*8+n], 0.f), w2[chunk*8+n], partial);
  __shared__ float red[16][17];
  red[eloc][chunk] = partial;
  __syncthreads();
  if(chunk==0){
    float s = b2[0];
    #pragma unroll
    for(int c2=0;c2<16;c2++) s += red[eloc][c2];
    tab[e] = s;
  }
}

// ------------- CPB bias eval: bilinear interp of tab at (u(px), v(py)) -------------
// Output layout: biasOut[bg][j][i] (same as old biasmlp; attn unchanged).
__global__ __launch_bounds__(256) void biaseval_kernel(
    const float* __restrict__ vgrid, const float* __restrict__ tab,
    float* __restrict__ biasOut){
  int t = threadIdx.x;
  int bg = blockIdx.x >> 6, jj = blockIdx.x & 63;
  float vx = vgrid[bg*128 + jj*2];
  float vy = vgrid[bg*128 + jj*2 + 1];
  int i0 = t*4;
  int gy = i0 >> 5, gx0 = i0 & 31;
  float py = (2.0f/31.0f)*(float)gy - 1.0f - vy;
  float v = copysignf(__logf(1.0f + fabsf(py)), py);
  float fv = (v - TU0) * TINV;
  int iv = (int)floorf(fv);
  iv = iv < 0 ? 0 : (iv > 62 ? 62 : iv);
  fv -= (float)iv;
  f32x4 res;
  #pragma unroll
  for(int c=0;c<4;c++){
    float px = (2.0f/31.0f)*(float)(gx0 + c) - 1.0f - vx;
    float u = copysignf(__logf(1.0f + fabsf(px)), px);
    float fu = (u - TU0) * TINV;
    int iu = (int)floorf(fu);
    iu = iu < 0 ? 0 : (iu > 62 ? 62 : iu);
    fu -= (float)iu;
    const float* p0 = &tab[iv*64 + iu];
    const float* p1 = p0 + 64;
    float a = fmaf(fu, p0[1] - p0[0], p0[0]);
    float b = fmaf(fu, p1[1] - p1[0], p1[0]);
    res[c] = fmaf(fv, b - a, a);
  }
  *(f32x4*)&biasOut[(size_t)bg*65536 + (size_t)jj*1024 + i0] = res;
}

// ------------- attention: softmax(q·K*scale + bias) @ V, output [b][p][ch] bf16 -------------
__global__ __launch_bounds__(256) void attn_kernel(
    const float* __restrict__ qb, const float* __restrict__ kb, const float* __restrict__ vb,
    const float* __restrict__ biasb, u16* __restrict__ obT){
  __shared__ float qT[64*65], kT[64*65], vT[64*65], bT[64*65];
  int t = threadIdx.x;
  int bg = blockIdx.x>>4, itile = blockIdx.x&15;
  int i0 = itile*64;
  size_t qBase = (size_t)bg*65536;        // == b*C*HW + g*64*HW
  for(int e=t;e<4096;e+=256){
    int d = e>>6, x = e&63;
    qT[d*65 + x] = qb[qBase + (size_t)d*HWPIX + i0 + x];
    kT[d*65 + x] = kb[(size_t)bg*4096 + e];
    vT[d*65 + x] = vb[(size_t)bg*4096 + e];
    bT[x*65 + d] = biasb[(size_t)bg*65536 + (size_t)d*1024 + i0 + x];  // d=j, x=il
  }
  __syncthreads();
  int lane = t&63, w = t>>6;
  int b = bg>>3, g = bg&7;
  for(int rr=0;rr<16;rr++){
    int il = w*16 + rr;
    int i = i0 + il;
    float qreg = qT[lane*65 + il];     // lane l holds q[i][d=l]
    float s0=0.f,s1=0.f,s2=0.f,s3=0.f;
    #pragma unroll 4
    for(int d=0;d<64;d+=4){
      s0 = fmaf(rdlane(qreg,d  ), kT[(d  )*65 + lane], s0);
      s1 = fmaf(rdlane(qreg,d+1), kT[(d+1)*65 + lane], s1);
      s2 = fmaf(rdlane(qreg,d+2), kT[(d+2)*65 + lane], s2);
      s3 = fmaf(rdlane(qreg,d+3), kT[(d+3)*65 + lane], s3);
    }
    float s = (s0+s1)+(s2+s3);
    s = s*SCALE + bT[il*65 + lane];
    float m = s;
    for(int msk=32;msk;msk>>=1) m = fmaxf(m, __shfl_xor(m, msk));
    float p = __expf(s - m);
    float l = p;
    for(int msk=32;msk;msk>>=1) l += __shfl_xor(l, msk);
    p = p / l;
    float o0=0.f,o1=0.f,o2=0.f,o3=0.f;
    #pragma unroll 4
    for(int j=0;j<64;j+=4){
      o0 = fmaf(rdlane(p,j  ), vT[lane*65 + j  ], o0);
      o1 = fmaf(rdlane(p,j+1), vT[lane*65 + j+1], o1);
      o2 = fmaf(rdlane(p,j+2), vT[lane*65 + j+2], o2);
      o3 = fmaf(rdlane(p,j+3), vT[lane*65 + j+3], o3);
    }
    obT[(size_t)b*524288 + (size_t)i*512 + g*64 + lane] = f2bf((o0+o1)+(o2+o3));
  }
}

extern "C" void kernel_launch(void* const* d_in, const int* in_sizes, int n_in,
                              void* d_out, int out_size, void* d_ws, size_t ws_size,
                              hipStream_t stream){
  const float* x    = (const float*)d_in[0];
  const float* n1g  = (const float*)d_in[1];
  const float* n1b  = (const float*)d_in[2];
  const float* n2g  = (const float*)d_in[3];
  const float* n2b  = (const float*)d_in[4];
  const float* qw   = (const float*)d_in[5];
  const float* kw   = (const float*)d_in[6];
  const float* vw   = (const float*)d_in[7];
  const float* dww  = (const float*)d_in[8];
  const float* dwb  = (const float*)d_in[9];
  const float* pww  = (const float*)d_in[10];
  const float* cw0  = (const float*)d_in[11];
  const float* cb0  = (const float*)d_in[12];
  const float* cw1  = (const float*)d_in[13];
  const float* cb1  = (const float*)d_in[14];
  const float* cw2  = (const float*)d_in[15];
  const float* cb2  = (const float*)d_in[16];
  const float* ow   = (const float*)d_in[17];
  const float* obb  = (const float*)d_in[18];
  const float* m1w  = (const float*)d_in[19];
  const float* m1bi = (const float*)d_in[20];
  const float* m2w  = (const float*)d_in[21];
  const float* m2bi = (const float*)d_in[22];
  float* out = (float*)d_out;          // reference output dtype is float32
  float* ws = (float*)d_ws;

  float* xn     = ws;                       // 1M f32: bn1 normalized (c-major, for sample)
  float* x2     = ws + 1048576;             // 1M f32: outproj out (res for mlp2, src for bn2)
  float* q      = ws + 2097152;             // 1M f32, dead after attn
  float* biasb  = ws + 3145728;             // 1M f32, dead after attn
  u16*   hT     = (u16*)(ws + 2097152);     // 4M u16 over dead {q,biasb}: mlp1 out [b][p][c2048]
  u16*   attnT  = (u16*)(ws + 4194304);     // 1M u16: attn out [b][p][c512]
  u16*   xnT    = (u16*)(ws + 4718592);     // 1M u16: bn1 T [bg][p][c64]; reused as bn2 T [b][p][c512]
  u16*   kvT    = (u16*)(ws + 5242880);     // 64K u16: [bg][p][c64]; region reused as CPB table after v-gemm
  float* tab    = ws + 5242880;             // 4096 f32 CPB table (aliases dead kvT)
  float* kbuf   = ws + 5275648;             // 64K f32
  float* vbuf   = ws + 5341184;             // 64K f32
  float* offg   = ws + 5406720;             // 64K f32 (aliased as bn stats when offg dead)
  float* bnAB   = offg;                     // 1024 f32 alias (disjoint lifetime)
  float* vgrid  = ws + 5472256;             // 2K f32
  u16*   wbf    = (u16*)(ws + 5474304);     // 2457600 u16 bf16 weights
  u16 *qwb = wbf, *kwb = wbf+32768, *vwb = wbf+65536, *owb = wbf+98304;
  u16 *m1wb = wbf+360448, *m2wb = wbf+1409024;

  cvtw_kernel<<<2400,256,0,stream>>>(qw,kw,vw,ow,m1w,m2w,wbf);
  bnstat_kernel<<<512,256,0,stream>>>(x, n1g, n1b, bnAB);
  bntrans_kernel<<<dim3(16,8,2),256,0,stream>>>(x, bnAB, xn, xnT, 0);
  gemm_lds<1,0><<<dim3(16,1,16),256,0,stream>>>(qwb, xnT, q, nullptr, nullptr, nullptr,
                                                64,64,1024, 7, 4096, 0);
  dwconv_kernel<<<256,256,0,stream>>>(q, dww, dwb, offg);
  pwgrid_kernel<<<16,64,0,stream>>>(offg, pww, vgrid);
  sample_kernel<<<dim3(16,4),256,0,stream>>>(xn, vgrid, kvT);
  gemm_lds<1,0><<<dim3(1,1,16),256,0,stream>>>(kwb, kvT, kbuf, nullptr, nullptr, nullptr,
                                               64,64,64, 7, 4096, 0);
  gemm_lds<1,0><<<dim3(1,1,16),256,0,stream>>>(vwb, kvT, vbuf, nullptr, nullptr, nullptr,
                                               64,64,64, 7, 4096, 0);
  // kvT dead from here; build CPB table into its region, then interpolate
  tabbuild_kernel<<<256,256,0,stream>>>(cw0, cb0, cw1, cb1, cw2, cb2, tab);
  biaseval_kernel<<<1024,256,0,stream>>>(vgrid, tab, biasb);
  attn_kernel<<<256,256,0,stream>>>(q, kbuf, vbuf, biasb, attnT);
  gemm_lds<1,0><<<dim3(16,8,2),256,0,stream>>>(owb, attnT, x2, nullptr, obb, x,
                                               512,512,1024, 0,0,0);
  bnstat_kernel<<<512,256,0,stream>>>(x2, n2g, n2b, bnAB);
  bntrans_kernel<<<dim3(16,8,2),256,0,stream>>>(x2, bnAB, nullptr, xnT, 1);
  // mlp1: NT=2 (64m x 128n tile, 16 MFMA per wave per k-iter), grid 512 blocks
  gemm_lds<2,1><<<dim3(8,32,2),256,0,stream>>>(m1wb, xnT, nullptr, hT, m1bi, nullptr,
                                               2048,512,1024, 0,0,1);
  gemm_lds<1,0><<<dim3(16,8,2),256,0,stream>>>(m2wb, hT, out, nullptr, m2bi, x2,
                                               512,2048,1024, 0,0,0);
}

// Round 15
// 218.707 us; speedup vs baseline: 1.3985x; 1.1434x over previous
//
#include <hip/hip_runtime.h>
#include <cstdint>
#include <cstddef>

// ---- problem constants (B=2, C=512, H=W=32, G=8, Cg=64, h2=w2=8) ----
#define BATCH 2
#define CCH   512
#define HWPIX 1024           // 32*32
#define SCALE 0.125f         // 64^-0.5
// CPB bias lookup table: F(u,v) on 64x64 grid over [-1.45,1.45]^2 (piecewise-linear MLP
// -> bilinear interp error ~1e-6; |u|,|v| <= log1p(3.143)=1.422 from |tanh|<1).
#define TU0  (-1.45f)
#define TDU  (2.9f/63.0f)
#define TINV (63.0f/2.9f)

typedef short bh8 __attribute__((ext_vector_type(8)));   // 8 x bf16 (4 VGPRs)
typedef float f32x4 __attribute__((ext_vector_type(4)));
typedef unsigned short u16;
typedef u16 us8 __attribute__((ext_vector_type(8)));     // 16B of bf16
typedef u16 us4 __attribute__((ext_vector_type(4)));     // 8B of bf16

__device__ __forceinline__ u16 f2bf(float f){
  unsigned u = __float_as_uint(f);
  unsigned r = (u + 0x7FFFu + ((u>>16)&1u))>>16;   // RNE
  return (u16)r;
}
__device__ __forceinline__ float geluf(float v){ return 0.5f*v*(1.0f + erff(v*0.70710678118654752f)); }

// ---------------- weight preconvert: f32 -> bf16, 6 segments concatenated ----------------
__global__ __launch_bounds__(256) void cvtw_kernel(
    const float* __restrict__ qw, const float* __restrict__ kw, const float* __restrict__ vw,
    const float* __restrict__ ow, const float* __restrict__ m1, const float* __restrict__ m2,
    u16* __restrict__ dst){
  int idx = (blockIdx.x*256 + threadIdx.x)*4;
  if(idx >= 2457600) return;
  const float* src; int off;
  if(idx < 32768){ src=qw; off=idx; }
  else if(idx <   65536){ src=kw; off=idx-32768; }
  else if(idx <   98304){ src=vw; off=idx-65536; }
  else if(idx <  360448){ src=ow; off=idx-98304; }
  else if(idx < 1409024){ src=m1; off=idx-360448; }
  else                  { src=m2; off=idx-1409024; }
  float4 v = *(const float4*)&src[off];
  us4 r = (us4){f2bf(v.x), f2bf(v.y), f2bf(v.z), f2bf(v.w)};
  *(us4*)&dst[idx] = r;
}

// ---------------- BatchNorm stats: per-channel scale/shift -> AB[1024] ----------------
__global__ __launch_bounds__(256) void bnstat_kernel(const float* __restrict__ src,
      const float* __restrict__ g, const float* __restrict__ bta, float* __restrict__ AB){
  int c = blockIdx.x; int t = threadIdx.x;
  float s=0.f, ss=0.f;
  for(int b=0;b<BATCH;b++){
    size_t base = (size_t)b*CCH*HWPIX + (size_t)c*HWPIX;
    for(int p=t;p<HWPIX;p+=256){
      float v = src[base+p];
      s += v; ss += v*v;
    }
  }
  for(int o=32;o;o>>=1){ s += __shfl_down(s,o); ss += __shfl_down(ss,o); }
  __shared__ float ls[4], lss[4];
  int w = t>>6, lane = t&63;
  if(lane==0){ ls[w]=s; lss[w]=ss; }
  __syncthreads();
  if(t==0){
    float S=ls[0]+ls[1]+ls[2]+ls[3], SS=lss[0]+lss[1]+lss[2]+lss[3];
    float m = S*(1.0f/2048.0f);
    float var = SS*(1.0f/2048.0f) - m*m;
    float r = rsqrtf(var + 1e-5f);
    AB[c]     = r*g[c];
    AB[512+c] = bta[c] - m*r*g[c];
  }
}

// ---------------- BN apply + transpose: src [b][ch][p] f32 -> dstT [n][k] bf16 (+opt f32 copy) ----------------
// tMode 0: dstT[(b*8+g)*65536 + p*64 + c]  (grouped, K=64)   tMode 1: dstT[b*524288 + p*512 + g*64 + c]
__global__ __launch_bounds__(256) void bntrans_kernel(const float* __restrict__ src,
      const float* __restrict__ AB, float* __restrict__ dstF, u16* __restrict__ dstT, int tMode){
  __shared__ float tile[64*65];
  int t = threadIdx.x;
  int p0 = blockIdx.x*64, gq = blockIdx.y, b = blockIdx.z;
  int pl = t&63, seg = t>>6;
  #pragma unroll
  for(int r=0;r<16;r++){
    int c = seg*16 + r;
    int ch = gq*64 + c;
    size_t a = (size_t)b*524288 + (size_t)ch*1024 + p0 + pl;
    float v = src[a]*AB[ch] + AB[512+ch];
    tile[c*65 + pl] = v;
    if(dstF) dstF[a] = v;
  }
  __syncthreads();
  int c = t&63;
  #pragma unroll
  for(int r=0;r<16;r++){
    int p = seg*16 + r;
    float v = tile[c*65 + p];
    size_t a = tMode ? ((size_t)b*524288 + (size_t)(p0+p)*512 + gq*64 + c)
                     : ((size_t)(b*8+gq)*65536 + (size_t)(p0+p)*64 + c);
    dstT[a] = f2bf(v);
  }
}

// ------- LDS-staged pipelined GEMM: out[b][m][n] = W[m][k] @ Xt, Xt is [n][k] bf16 -------
// NT = 16-col n-subtiles per wave. TOUT: 0 = f32 [m][n]; 1 = bf16 transposed [n][m];
// 2 = BOTH (f32 [m][n] unscaled + bf16 [n][m] scaled by SCALE — for attention Q).
template<int NT, int TOUT>
__global__ __launch_bounds__(256,4) void gemm_lds(
    const u16* __restrict__ W, const u16* __restrict__ Xt,
    float* __restrict__ outF, u16* __restrict__ outT,
    const float* __restrict__ bias, const float* __restrict__ resF,
    int M, int K, int Nb, int wMask, int wStride, int doGelu){
  __shared__ __align__(16) u16 xS[64*NT*64];   // [row][kb' swizzled], 8*NT KB
  __shared__ __align__(16) u16 wS[64*64];      // 8KB
  int t = threadIdx.x;
  int w = t>>6, lane = t&63, l15 = lane&15, quad = lane>>4;
  int n0 = blockIdx.x*(64*NT), m0 = blockIdx.y*64, batch = blockIdx.z;
  const u16* Wg = W + (size_t)(batch & wMask)*wStride + (size_t)m0*K;
  const u16* Xg = Xt + (size_t)batch*Nb*K + (size_t)n0*K;
  const u16* pX[2*NT]; u16* sX[2*NT];
  #pragma unroll
  for(int p=0;p<2*NT;p++){
    int row = (p*256 + t)>>3, kb = t&7;
    pX[p] = Xg + (size_t)row*K + kb*8;
    sX[p] = &xS[(row*8 + (kb ^ (row&7)))*8];
  }
  int row0 = t>>3,        kb0 = t&7;
  int row1 = (256+t)>>3,  kb1 = t&7;
  const u16* pW0 = Wg + (size_t)row0*K + kb0*8;
  const u16* pW1 = Wg + (size_t)row1*K + kb1*8;
  u16* sW0 = &wS[(row0*8 + (kb0 ^ (row0&7)))*8];
  u16* sW1 = &wS[(row1*8 + (kb1 ^ (row1&7)))*8];
  f32x4 acc[4][NT];
  #pragma unroll
  for(int mt=0;mt<4;mt++)
    #pragma unroll
    for(int nt=0;nt<NT;nt++) acc[mt][nt] = (f32x4){0.f,0.f,0.f,0.f};
  us8 rx[2*NT], rw0, rw1;
  #pragma unroll
  for(int p=0;p<2*NT;p++) rx[p] = *(const us8*)pX[p];
  rw0 = *(const us8*)pW0; rw1 = *(const us8*)pW1;
  for(int kc=0;kc<K;kc+=64){
    #pragma unroll
    for(int p=0;p<2*NT;p++) *(us8*)sX[p] = rx[p];
    *(us8*)sW0 = rw0;  *(us8*)sW1 = rw1;
    __syncthreads();
    if(kc+64 < K){
      #pragma unroll
      for(int p=0;p<2*NT;p++) rx[p] = *(const us8*)(pX[p] + kc+64);
      rw0 = *(const us8*)(pW0 + kc+64);  rw1 = *(const us8*)(pW1 + kc+64);
    }
    #pragma unroll
    for(int ks=0;ks<2;ks++){
      bh8 bF[NT];
      #pragma unroll
      for(int nt=0;nt<NT;nt++){
        int rb = (w*NT + nt)*16 + l15;
        bF[nt] = *(const bh8*)&xS[rb*64 + ((ks*4+quad) ^ (rb&7))*8];
      }
      #pragma unroll
      for(int mt=0;mt<4;mt++){
        int ra = mt*16 + l15;
        bh8 aF = *(const bh8*)&wS[ra*64 + ((ks*4+quad) ^ (ra&7))*8];
        #pragma unroll
        for(int nt=0;nt<NT;nt++)
          acc[mt][nt] = __builtin_amdgcn_mfma_f32_16x16x32_bf16(aF, bF[nt], acc[mt][nt], 0,0,0);
      }
    }
    __syncthreads();
  }
  if(TOUT==1){
    size_t oB = (size_t)batch*Nb*(size_t)M;
    #pragma unroll
    for(int nt=0;nt<NT;nt++){
      int n = n0 + (w*NT + nt)*16 + l15;
      #pragma unroll
      for(int mt=0;mt<4;mt++){
        int m = m0 + mt*16 + quad*4;
        us4 pk;
        #pragma unroll
        for(int reg=0;reg<4;reg++){
          float v = acc[mt][nt][reg];
          if(bias) v += bias[m+reg];
          if(doGelu) v = geluf(v);
          pk[reg] = f2bf(v);
        }
        *(us4*)&outT[oB + (size_t)n*M + m] = pk;
      }
    }
  } else if(TOUT==2){
    size_t oBF = (size_t)batch*(size_t)M*Nb;
    size_t oBT = (size_t)batch*Nb*(size_t)M;
    #pragma unroll
    for(int nt=0;nt<NT;nt++){
      int n = n0 + (w*NT + nt)*16 + l15;
      #pragma unroll
      for(int mt=0;mt<4;mt++){
        int m = m0 + mt*16 + quad*4;
        us4 pk;
        #pragma unroll
        for(int reg=0;reg<4;reg++){
          float v = acc[mt][nt][reg];
          outF[oBF + (size_t)(m+reg)*Nb + n] = v;
          pk[reg] = f2bf(v*SCALE);
        }
        *(us4*)&outT[oBT + (size_t)n*M + m] = pk;
      }
    }
  } else {
    size_t oB = (size_t)batch*(size_t)M*Nb;
    #pragma unroll
    for(int nt=0;nt<NT;nt++){
      int n = n0 + (w*NT + nt)*16 + l15;
      #pragma unroll
      for(int mt=0;mt<4;mt++)
        #pragma unroll
        for(int reg=0;reg<4;reg++){
          int m = m0 + mt*16 + quad*4 + reg;      // C/D: col=lane&15, row=quad*4+reg
          float v = acc[mt][nt][reg];
          if(bias) v += bias[m];
          if(doGelu) v = geluf(v);
          size_t a = oB + (size_t)m*Nb + n;
          if(resF) v += resF[a];
          outF[a] = v;
        }
    }
  }
}

// ------------- depthwise 6x6 stride-4 pad-1 conv + exact gelu -------------
__global__ __launch_bounds__(256) void dwconv_kernel(const float* __restrict__ q,
    const float* __restrict__ dw, const float* __restrict__ dwb, float* __restrict__ offg){
  int t = threadIdx.x;
  int bgc = blockIdx.x*4 + (t>>6);       // 0..1023 = bg*64 + c
  int c = bgc & 63;
  int pix = t&63;
  int oy = pix>>3, ox = pix&7;
  const float* img = q + (size_t)bgc*HWPIX;
  float acc = dwb[c];
  #pragma unroll
  for(int ky=0;ky<6;ky++){
    int y = oy*4 - 1 + ky;
    if(y<0 || y>31) continue;
    #pragma unroll
    for(int kx=0;kx<6;kx++){
      int x = ox*4 - 1 + kx;
      if(x<0 || x>31) continue;
      acc = fmaf(img[y*32 + x], dw[c*36 + ky*6 + kx], acc);
    }
  }
  offg[(size_t)bgc*64 + pix] = geluf(acc);
}

// ------------- pointwise 64->2, tanh*4, build sampling grid -------------
__global__ __launch_bounds__(64) void pwgrid_kernel(const float* __restrict__ offg,
    const float* __restrict__ pw, float* __restrict__ vgrid){
  int bg = blockIdx.x; int p = threadIdx.x;
  float a0=0.f, a1=0.f;
  for(int c=0;c<64;c++){
    float v = offg[(size_t)bg*4096 + c*64 + p];
    a0 = fmaf(v, pw[c], a0);
    a1 = fmaf(v, pw[64+c], a1);
  }
  float o0 = tanhf(a0)*4.0f, o1 = tanhf(a1)*4.0f;
  float gx = (float)(p&7), gy = (float)(p>>3);
  float vxx = (2.0f/7.0f)*(gx + o0) - 1.0f;
  float vyy = (2.0f/7.0f)*(gy + o1) - 1.0f;
  vgrid[bg*128 + p*2]     = vxx;
  vgrid[bg*128 + p*2 + 1] = vyy;
}

// ------------- bilinear grid sample (zero padding), bf16 [p][c] output -------------
__device__ __forceinline__ float fetchpix(const float* img, int ix, int iy){
  return (ix>=0 && ix<32 && iy>=0 && iy<32) ? img[iy*32+ix] : 0.0f;
}
__global__ __launch_bounds__(256) void sample_kernel(const float* __restrict__ xn,
    const float* __restrict__ vgrid, u16* __restrict__ kvT){
  int bg = blockIdx.x; int t = threadIdx.x;
  int p = t&63, cblk = t>>6;
  int cbase = blockIdx.y*16 + cblk*4;
  float vx = vgrid[bg*128 + p*2], vy = vgrid[bg*128 + p*2+1];
  float xs = ((vx + 1.0f)*32.0f - 1.0f)*0.5f;
  float ys = ((vy + 1.0f)*32.0f - 1.0f)*0.5f;
  float x0 = floorf(xs), y0 = floorf(ys);
  float wx = xs - x0, wy = ys - y0;
  int ix0 = (int)x0, iy0 = (int)y0;
  int b = bg>>3, g = bg&7;
  float w00 = (1.f-wx)*(1.f-wy), w10 = wx*(1.f-wy), w01 = (1.f-wx)*wy, w11 = wx*wy;
  us4 tmp;
  #pragma unroll
  for(int cc=0;cc<4;cc++){
    int c = cbase + cc;
    const float* img = xn + (size_t)b*CCH*HWPIX + (size_t)(g*64+c)*HWPIX;
    float acc = w00*fetchpix(img,ix0,iy0)   + w10*fetchpix(img,ix0+1,iy0)
              + w01*fetchpix(img,ix0,iy0+1) + w11*fetchpix(img,ix0+1,iy0+1);
    tmp[cc] = f2bf(acc);
  }
  *(us4*)&kvT[(size_t)bg*4096 + p*64 + cbase] = tmp;
}

// ------------- CPB table build: F(u,v) = MLP(u,v) on 64x64 grid -------------
__global__ __launch_bounds__(256) void tabbuild_kernel(
    const float* __restrict__ w0, const float* __restrict__ b0,
    const float* __restrict__ w1, const float* __restrict__ b1,
    const float* __restrict__ w2, const float* __restrict__ b2,
    float* __restrict__ tab){
  int t = threadIdx.x;
  int eloc = t & 15, chunk = t >> 4;           // 16 entries x 16 chunks of 8 n
  int e = blockIdx.x*16 + eloc;                // 0..4095
  int iu = e & 63, iv = e >> 6;
  float u = TU0 + iu*TDU, v = TU0 + iv*TDU;
  float acc[8] = {0.f,0.f,0.f,0.f,0.f,0.f,0.f,0.f};
  for(int k=0;k<128;k++){
    float h0 = fmaxf(fmaf(u, w0[k], fmaf(v, w0[128+k], b0[k])), 0.f);
    const float* wr = &w1[k*128 + chunk*8];
    #pragma unroll
    for(int n=0;n<8;n++) acc[n] = fmaf(h0, wr[n], acc[n]);
  }
  float partial = 0.f;
  #pragma unroll
  for(int n=0;n<8;n++)
    partial = fmaf(fmaxf(acc[n] + b1[chunk*8+n], 0.f), w2[chunk*8+n], partial);
  __shared__ float red[16][17];
  red[eloc][chunk] = partial;
  __syncthreads();
  if(chunk==0){
    float s = b2[0];
    #pragma unroll
    for(int c2=0;c2<16;c2++) s += red[eloc][c2];
    tab[e] = s;
  }
}

// ------------- CPB bias eval: bilinear interp of tab at (u(px), v(py)) -------------
__global__ __launch_bounds__(256) void biaseval_kernel(
    const float* __restrict__ vgrid, const float* __restrict__ tab,
    float* __restrict__ biasOut){
  int t = threadIdx.x;
  int bg = blockIdx.x >> 6, jj = blockIdx.x & 63;
  float vx = vgrid[bg*128 + jj*2];
  float vy = vgrid[bg*128 + jj*2 + 1];
  int i0 = t*4;
  int gy = i0 >> 5, gx0 = i0 & 31;
  float py = (2.0f/31.0f)*(float)gy - 1.0f - vy;
  float v = copysignf(__logf(1.0f + fabsf(py)), py);
  float fv = (v - TU0) * TINV;
  int iv = (int)floorf(fv);
  iv = iv < 0 ? 0 : (iv > 62 ? 62 : iv);
  fv -= (float)iv;
  f32x4 res;
  #pragma unroll
  for(int c=0;c<4;c++){
    float px = (2.0f/31.0f)*(float)(gx0 + c) - 1.0f - vx;
    float u = copysignf(__logf(1.0f + fabsf(px)), px);
    float fu = (u - TU0) * TINV;
    int iu = (int)floorf(fu);
    iu = iu < 0 ? 0 : (iu > 62 ? 62 : iu);
    fu -= (float)iu;
    const float* p0 = &tab[iv*64 + iu];
    const float* p1 = p0 + 64;
    float a = fmaf(fu, p0[1] - p0[0], p0[0]);
    float b = fmaf(fu, p1[1] - p1[0], p1[0]);
    res[c] = fmaf(fv, b - a, a);
  }
  *(f32x4*)&biasOut[(size_t)bg*65536 + (size_t)jj*1024 + i0] = res;
}

// ------------- MFMA attention: O = softmax(Q·K^T + bias) V -------------
// Q pre-scaled by 0.125 (exact exponent shift, done in q-gemm TOUT=2 epilogue).
// qTb bf16 [bg][p][d] (A layout), kTb bf16 [bg][j][d] (B layout for QK^T),
// vb f32 [bg][d][j] (B layout for PV after bf16 staging), bias as MFMA C operand.
__global__ __launch_bounds__(256) void attn_kernel(
    const u16* __restrict__ qTb, const u16* __restrict__ kTb, const float* __restrict__ vb,
    const float* __restrict__ biasb, u16* __restrict__ obT){
  __shared__ __align__(16) u16 qS[64*64], kS[64*64];   // swizzled (gemm pattern)
  __shared__ __align__(16) u16 vS[64*72], pS[64*72];   // pad-72 rows
  int t = threadIdx.x;
  int w = t>>6, lane = t&63, l15 = lane&15, quad = lane>>4;
  int bg = blockIdx.x>>4, itile = blockIdx.x&15;
  int i0 = itile*64;
  #pragma unroll
  for(int p=0;p<2;p++){
    int idx = p*256 + t;
    int row = idx>>3, kb = t&7;
    int sw = ((kb ^ (row&7)))*8;
    *(us8*)&qS[row*64 + sw] = *(const us8*)&qTb[(size_t)bg*65536 + (size_t)(i0+row)*64 + kb*8];
    *(us8*)&kS[row*64 + sw] = *(const us8*)&kTb[(size_t)bg*4096  + (size_t)row*64      + kb*8];
  }
  for(int e=t;e<4096;e+=256){
    int d = e>>6, j = e&63;
    vS[d*72 + j] = f2bf(vb[(size_t)bg*4096 + e]);
  }
  __syncthreads();
  // ---- S = Q·K^T (+bias via C operand). Wave w: rows i = i0 + w*16 + (0..15). ----
  f32x4 sAcc[4];
  #pragma unroll
  for(int jt=0;jt<4;jt++){
    int jg = jt*16 + l15;
    sAcc[jt] = *(const f32x4*)&biasb[(size_t)bg*65536 + (size_t)jg*1024 + i0 + w*16 + quad*4];
  }
  int ra = w*16 + l15;
  #pragma unroll
  for(int ks=0;ks<2;ks++){
    bh8 aF = *(const bh8*)&qS[ra*64 + ((ks*4+quad) ^ (ra&7))*8];
    #pragma unroll
    for(int jt=0;jt<4;jt++){
      int rb = jt*16 + l15;
      bh8 bF = *(const bh8*)&kS[rb*64 + ((ks*4+quad) ^ (rb&7))*8];
      sAcc[jt] = __builtin_amdgcn_mfma_f32_16x16x32_bf16(aF, bF, sAcc[jt], 0,0,0);
    }
  }
  // ---- softmax over j (row i = quad*4+reg within wave; j = jt*16 + l15) ----
  #pragma unroll
  for(int reg=0;reg<4;reg++){
    float m = fmaxf(fmaxf(sAcc[0][reg], sAcc[1][reg]), fmaxf(sAcc[2][reg], sAcc[3][reg]));
    m = fmaxf(m, __shfl_xor(m, 1));
    m = fmaxf(m, __shfl_xor(m, 2));
    m = fmaxf(m, __shfl_xor(m, 4));
    m = fmaxf(m, __shfl_xor(m, 8));
    float li = 0.f;
    #pragma unroll
    for(int jt=0;jt<4;jt++){
      float e = __expf(sAcc[jt][reg] - m);
      sAcc[jt][reg] = e;
      li += e;
    }
    li += __shfl_xor(li, 1);
    li += __shfl_xor(li, 2);
    li += __shfl_xor(li, 4);
    li += __shfl_xor(li, 8);
    float inv = 1.0f / li;
    #pragma unroll
    for(int jt=0;jt<4;jt++) sAcc[jt][reg] *= inv;
  }
  // ---- P -> LDS [i][j] (own wave's rows only; per-wave LDS ordering via lgkmcnt) ----
  #pragma unroll
  for(int jt=0;jt<4;jt++)
    #pragma unroll
    for(int reg=0;reg<4;reg++)
      pS[(w*16 + quad*4 + reg)*72 + jt*16 + l15] = f2bf(sAcc[jt][reg]);
  __syncthreads();
  // ---- O = P·V: A = P[i][k=j], B = V[k=j][n=d] (vS rows d? no: vS[d][j], lane n=d reads row d over j) ----
  f32x4 oAcc[4];
  #pragma unroll
  for(int dt=0;dt<4;dt++) oAcc[dt] = (f32x4){0.f,0.f,0.f,0.f};
  int rp = w*16 + l15;
  #pragma unroll
  for(int ks=0;ks<2;ks++){
    bh8 aP = *(const bh8*)&pS[rp*72 + ks*32 + quad*8];
    #pragma unroll
    for(int dt=0;dt<4;dt++){
      bh8 bV = *(const bh8*)&vS[(dt*16 + l15)*72 + ks*32 + quad*8];
      oAcc[dt] = __builtin_amdgcn_mfma_f32_16x16x32_bf16(aP, bV, oAcc[dt], 0,0,0);
    }
  }
  // ---- store O: D[i=quad*4+reg][d=l15] -> attnT[b][i][g*64+d] ----
  int b = bg>>3, g = bg&7;
  #pragma unroll
  for(int dt=0;dt<4;dt++)
    #pragma unroll
    for(int reg=0;reg<4;reg++){
      int i = i0 + w*16 + quad*4 + reg;
      obT[(size_t)b*524288 + (size_t)i*512 + g*64 + dt*16 + l15] = f2bf(oAcc[dt][reg]);
    }
}

extern "C" void kernel_launch(void* const* d_in, const int* in_sizes, int n_in,
                              void* d_out, int out_size, void* d_ws, size_t ws_size,
                              hipStream_t stream){
  const float* x    = (const float*)d_in[0];
  const float* n1g  = (const float*)d_in[1];
  const float* n1b  = (const float*)d_in[2];
  const float* n2g  = (const float*)d_in[3];
  const float* n2b  = (const float*)d_in[4];
  const float* qw   = (const float*)d_in[5];
  const float* kw   = (const float*)d_in[6];
  const float* vw   = (const float*)d_in[7];
  const float* dww  = (const float*)d_in[8];
  const float* dwb  = (const float*)d_in[9];
  const float* pww  = (const float*)d_in[10];
  const float* cw0  = (const float*)d_in[11];
  const float* cb0  = (const float*)d_in[12];
  const float* cw1  = (const float*)d_in[13];
  const float* cb1  = (const float*)d_in[14];
  const float* cw2  = (const float*)d_in[15];
  const float* cb2  = (const float*)d_in[16];
  const float* ow   = (const float*)d_in[17];
  const float* obb  = (const float*)d_in[18];
  const float* m1w  = (const float*)d_in[19];
  const float* m1bi = (const float*)d_in[20];
  const float* m2w  = (const float*)d_in[21];
  const float* m2bi = (const float*)d_in[22];
  float* out = (float*)d_out;          // reference output dtype is float32
  float* ws = (float*)d_ws;

  float* xn     = ws;                       // 1M f32: bn1 normalized (c-major, for sample)
  float* x2     = ws + 1048576;             // 1M f32: outproj out (res for mlp2, src for bn2)
  float* q      = ws + 2097152;             // 1M f32 [bg][c][p], dead after pwgrid (attn uses qTb)
  float* biasb  = ws + 3145728;             // 1M f32, dead after attn
  u16*   hT     = (u16*)(ws + 2097152);     // 4M u16 over dead {q,biasb}: mlp1 out [b][p][c2048]
  u16*   attnT  = (u16*)(ws + 4194304);     // 1M u16: attn out [b][p][c512]
  u16*   xnT    = (u16*)(ws + 4718592);     // 1M u16: bn1 T [bg][p][c64]; reused as bn2 T [b][p][c512]
  u16*   kvT    = (u16*)(ws + 5242880);     // 64K u16: [bg][p][c64]; reused as CPB table after v-gemm
  float* tab    = ws + 5242880;             // 4096 f32 CPB table (aliases dead kvT)
  u16*   kTb    = (u16*)(ws + 5275648);     // 64K u16: k bf16 [bg][j][d]
  float* vbuf   = ws + 5341184;             // 64K f32 [bg][d][j]
  float* offg   = ws + 5406720;             // 64K f32 (aliased as bn stats when offg dead)
  float* bnAB   = offg;                     // 1024 f32 alias (disjoint lifetime)
  float* vgrid  = ws + 5472256;             // 2K f32
  u16*   wbf    = (u16*)(ws + 5474304);     // 2457600 u16 bf16 weights
  u16*   qTb    = (u16*)(ws + 6703104);     // 1M u16: q bf16 [bg][p][d], pre-scaled by 0.125
  u16 *qwb = wbf, *kwb = wbf+32768, *vwb = wbf+65536, *owb = wbf+98304;
  u16 *m1wb = wbf+360448, *m2wb = wbf+1409024;

  cvtw_kernel<<<2400,256,0,stream>>>(qw,kw,vw,ow,m1w,m2w,wbf);
  bnstat_kernel<<<512,256,0,stream>>>(x, n1g, n1b, bnAB);
  bntrans_kernel<<<dim3(16,8,2),256,0,stream>>>(x, bnAB, xn, xnT, 0);
  // q: dual output — f32 [bg][c][p] for dwconv + bf16 [bg][p][d] (x0.125) for MFMA attn
  gemm_lds<1,2><<<dim3(16,1,16),256,0,stream>>>(qwb, xnT, q, qTb, nullptr, nullptr,
                                                64,64,1024, 7, 4096, 0);
  dwconv_kernel<<<256,256,0,stream>>>(q, dww, dwb, offg);
  pwgrid_kernel<<<16,64,0,stream>>>(offg, pww, vgrid);
  sample_kernel<<<dim3(16,4),256,0,stream>>>(xn, vgrid, kvT);
  // k: bf16 transposed [bg][j][d] (B layout for QK^T)
  gemm_lds<1,1><<<dim3(1,1,16),256,0,stream>>>(kwb, kvT, nullptr, kTb, nullptr, nullptr,
                                               64,64,64, 7, 4096, 0);
  // v: f32 [bg][d][j] (B layout for PV)
  gemm_lds<1,0><<<dim3(1,1,16),256,0,stream>>>(vwb, kvT, vbuf, nullptr, nullptr, nullptr,
                                               64,64,64, 7, 4096, 0);
  // kvT dead from here; build CPB table into its region, then interpolate
  tabbuild_kernel<<<256,256,0,stream>>>(cw0, cb0, cw1, cb1, cw2, cb2, tab);
  biaseval_kernel<<<1024,256,0,stream>>>(vgrid, tab, biasb);
  attn_kernel<<<256,256,0,stream>>>(qTb, kTb, vbuf, biasb, attnT);
  gemm_lds<1,0><<<dim3(16,8,2),256,0,stream>>>(owb, attnT, x2, nullptr, obb, x,
                                               512,512,1024, 0,0,0);
  bnstat_kernel<<<512,256,0,stream>>>(x2, n2g, n2b, bnAB);
  bntrans_kernel<<<dim3(16,8,2),256,0,stream>>>(x2, bnAB, nullptr, xnT, 1);
  // mlp1: NT=2 (64m x 128n tile), grid 512 blocks
  gemm_lds<2,1><<<dim3(8,32,2),256,0,stream>>>(m1wb, xnT, nullptr, hT, m1bi, nullptr,
                                               2048,512,1024, 0,0,1);
  gemm_lds<1,0><<<dim3(16,8,2),256,0,stream>>>(m2wb, hT, out, nullptr, m2bi, x2,
                                               512,2048,1024, 0,0,0);
}